// Round 2
// baseline (2307.107 us; speedup 1.0000x reference)
//
#include <hip/hip_runtime.h>
#include <math.h>

#define B_ 2
#define C_ 256
#define T_ 16
#define H_ 28
#define W_ 28
#define HW_ 784
#define RC_ 16
#define CT_STRIDE (T_*HW_)   // stride between channels in [B,C,T,H,W]

// ---------------- Kernel 1: pointwise convs  x2 = W2 @ x (256ch), xr = Wd @ x (16ch) ----
#define K1_PT 28
__global__ __launch_bounds__(256) void k1_pointwise(
    const float* __restrict__ x, const float* __restrict__ W2,
    const float* __restrict__ Wd, float* __restrict__ x2, float* __restrict__ xr)
{
  __shared__ float Xls[C_][K1_PT];
  const int tid = threadIdx.x;
  const int bt  = blockIdx.y;
  const int b = bt >> 4, t = bt & 15;
  const int p0 = blockIdx.x * K1_PT;
  const float* xbase = x + ((size_t)b*C_*T_ + t)*HW_ + p0;
  for (int idx = tid; idx < C_*K1_PT; idx += 256) {
    int c = idx / K1_PT, p = idx - c*K1_PT;
    Xls[c][p] = xbase[(size_t)c*CT_STRIDE + p];
  }
  __syncthreads();
  const int o = tid;
  float acc[K1_PT];
  #pragma unroll
  for (int p = 0; p < K1_PT; ++p) acc[p] = 0.f;
  const float* wrow = W2 + o*C_;
  for (int c0 = 0; c0 < C_; c0 += 8) {
    float4 wA = *(const float4*)(wrow + c0);
    float4 wB = *(const float4*)(wrow + c0 + 4);
    float wv[8] = {wA.x, wA.y, wA.z, wA.w, wB.x, wB.y, wB.z, wB.w};
    #pragma unroll
    for (int cc = 0; cc < 8; ++cc) {
      #pragma unroll
      for (int p = 0; p < K1_PT; ++p)
        acc[p] += wv[cc] * Xls[c0+cc][p];
    }
  }
  float* orow = x2 + ((size_t)(b*C_ + o)*T_ + t)*HW_ + p0;
  #pragma unroll
  for (int p = 0; p < K1_PT; ++p) orow[p] = acc[p];

  // xr: RC_ x K1_PT outputs per block
  for (int e = tid; e < RC_*K1_PT; e += 256) {
    int r = e / K1_PT, p = e - r*K1_PT;
    const float* wdr = Wd + r*C_;
    float a = 0.f;
    for (int c0 = 0; c0 < C_; c0 += 4) {
      float4 wv4 = *(const float4*)(wdr + c0);
      a += wv4.x*Xls[c0][p] + wv4.y*Xls[c0+1][p] + wv4.z*Xls[c0+2][p] + wv4.w*Xls[c0+3][p];
    }
    xr[((size_t)(b*RC_ + r)*T_ + t)*HW_ + p0 + p] = a;
  }
}

// ---------------- Kernel 2: 3x dilated depthwise 3D conv on xr, combined ---------------
__global__ __launch_bounds__(256) void k2_dwconv(
    const float* __restrict__ xr, const float* __restrict__ K1w,
    const float* __restrict__ K2w, const float* __restrict__ K3w,
    const float* __restrict__ wts, float* __restrict__ agg)
{
  __shared__ float slab[9][HW_];
  __shared__ float kw[3][81];
  const int tid = threadIdx.x;
  const int t  = blockIdx.x;
  const int br = blockIdx.y;           // b*RC + r
  const int r = br & 15;
  const size_t chbase = (size_t)br * T_ * HW_;
  for (int idx = tid; idx < 9*HW_; idx += 256) {
    int kd = idx / HW_, pp = idx - kd*HW_;
    int tt = t + kd - 4;
    slab[kd][pp] = (tt >= 0 && tt < T_) ? xr[chbase + (size_t)tt*HW_ + pp] : 0.f;
  }
  for (int idx = tid; idx < 3*81; idx += 256) {
    int kk = idx / 81, rem = idx - kk*81;
    const float* Ksrc = (kk == 0) ? K1w : ((kk == 1) ? K2w : K3w);
    kw[kk][rem] = Ksrc[r*81 + rem];
  }
  __syncthreads();
  const float w0 = wts[0], w1 = wts[1], w2v = wts[2];
  for (int p = tid; p < HW_; p += 256) {
    int h = p / W_, w = p - h*W_;
    float s0 = 0.f, s1 = 0.f, s2 = 0.f;
    for (int kd = 0; kd < 9; ++kd) {
      #pragma unroll
      for (int kh = 0; kh < 3; ++kh) {
        #pragma unroll
        for (int kwi = 0; kwi < 3; ++kwi) {
          const int widx = kd*9 + kh*3 + kwi;
          { int hh = h + (kh-1), ww = w + (kwi-1);
            if (hh >= 0 && hh < H_ && ww >= 0 && ww < W_)
              s0 += kw[0][widx] * slab[kd][hh*W_ + ww]; }
          { int hh = h + (kh-1)*2, ww = w + (kwi-1)*2;
            if (hh >= 0 && hh < H_ && ww >= 0 && ww < W_)
              s1 += kw[1][widx] * slab[kd][hh*W_ + ww]; }
          { int hh = h + (kh-1)*3, ww = w + (kwi-1)*3;
            if (hh >= 0 && hh < H_ && ww >= 0 && ww < W_)
              s2 += kw[2][widx] * slab[kd][hh*W_ + ww]; }
        }
      }
    }
    agg[chbase + (size_t)t*HW_ + p] = w0*s0 + w1*s1 + w2v*s2;
  }
}

// ---------------- Kernel 3: fused sigmoid-attention (both temporal dirs) ---------------
// features1[b,c,t,p] = sum_dir w2[dir] * sum_q (sigma(sum_k x[k,p]*x2s[k,q]) - 0.5) * x2s[c,q]
#define A_TM 28
#define A_TN 16
__global__ __launch_bounds__(256) void k3_attn(
    const float* __restrict__ x, const float* __restrict__ x2,
    const float* __restrict__ w2arr, float* __restrict__ outF)
{
  __shared__ float Qls[C_][A_TM];       // [channel][query]
  __shared__ float Kls[C_][A_TN+1];     // [channel][key], padded
  __shared__ float Pls[A_TM][A_TN];
  const int tid = threadIdx.x;
  const int bt  = blockIdx.y;
  const int b = bt >> 4, t = bt & 15;
  const int p0 = blockIdx.x * A_TM;
  const float* qbase = x + ((size_t)b*C_*T_ + t)*HW_ + p0;
  for (int idx = tid; idx < C_*A_TM; idx += 256) {
    int c = idx / A_TM, i = idx - c*A_TM;
    Qls[c][i] = qbase[(size_t)c*CT_STRIDE + i];
  }
  float acc[A_TM];
  #pragma unroll
  for (int i = 0; i < A_TM; ++i) acc[i] = 0.f;
  const float wd0 = w2arr[0], wd1 = w2arr[1];

  for (int dir = 0; dir < 2; ++dir) {
    const int ts = (dir == 0) ? (t < T_-1 ? t+1 : T_-1) : (t > 0 ? t-1 : 0);
    const float wdir = (dir == 0) ? wd0 : wd1;
    const float* kbase = x2 + ((size_t)b*C_*T_ + ts)*HW_;
    for (int q0 = 0; q0 < HW_; q0 += A_TN) {   // 49 exact tiles
      __syncthreads();   // previous PV done before Kls overwrite
      for (int idx = tid; idx < C_*A_TN; idx += 256) {
        int c = idx >> 4, j = idx & 15;
        Kls[c][j] = kbase[(size_t)c*CT_STRIDE + q0 + j];
      }
      __syncthreads();
      // scores + sigmoid
      for (int e = tid; e < A_TM*A_TN; e += 256) {
        int i = e >> 4, j = e & 15;
        float s = 0.f;
        #pragma unroll 8
        for (int k = 0; k < C_; ++k)
          s += Qls[k][i] * Kls[k][j];
        float sig = 1.f / (1.f + __expf(-s));
        Pls[i][j] = wdir * (sig - 0.5f);
      }
      __syncthreads();
      // PV: thread owns channel c = tid
      #pragma unroll
      for (int jj = 0; jj < A_TN; jj += 4) {
        float v0 = Kls[tid][jj+0];
        float v1 = Kls[tid][jj+1];
        float v2 = Kls[tid][jj+2];
        float v3 = Kls[tid][jj+3];
        #pragma unroll
        for (int i = 0; i < A_TM; ++i) {
          float4 pv = *(const float4*)&Pls[i][jj];
          acc[i] += pv.x*v0 + pv.y*v1 + pv.z*v2 + pv.w*v3;
        }
      }
    }
  }
  float* obase = outF + ((size_t)(b*C_ + tid)*T_ + t)*HW_ + p0;
  #pragma unroll
  for (int i = 0; i < A_TM; ++i) obase[i] = acc[i];
}

// ---------------- Kernel 4: gate = sigma(W_back @ agg) - 0.5 ; out *= gate -------------
#define K4_PT 112
__global__ __launch_bounds__(256) void k4_gate(
    const float* __restrict__ agg, const float* __restrict__ Wb,
    float* __restrict__ out)
{
  __shared__ float aggl[RC_][K4_PT];
  const int tid = threadIdx.x;
  const int bt  = blockIdx.y;
  const int b = bt >> 4, t = bt & 15;
  const int p0 = blockIdx.x * K4_PT;
  for (int idx = tid; idx < RC_*K4_PT; idx += 256) {
    int r = idx / K4_PT, p = idx - r*K4_PT;
    aggl[r][p] = agg[((size_t)(b*RC_ + r)*T_ + t)*HW_ + p0 + p];
  }
  __syncthreads();
  const int o = tid;
  float wb[RC_];
  #pragma unroll
  for (int r4 = 0; r4 < RC_; r4 += 4) {
    float4 v = *(const float4*)(Wb + o*RC_ + r4);
    wb[r4] = v.x; wb[r4+1] = v.y; wb[r4+2] = v.z; wb[r4+3] = v.w;
  }
  float* orow = out + ((size_t)(b*C_ + o)*T_ + t)*HW_ + p0;
  for (int p = 0; p < K4_PT; ++p) {
    float g = 0.f;
    #pragma unroll
    for (int r = 0; r < RC_; ++r) g += wb[r] * aggl[r][p];
    float sig = 1.f / (1.f + __expf(-g));
    orow[p] *= (sig - 0.5f);
  }
}

extern "C" void kernel_launch(void* const* d_in, const int* in_sizes, int n_in,
                              void* d_out, int out_size, void* d_ws, size_t ws_size,
                              hipStream_t stream)
{
  const float* x     = (const float*)d_in[0];
  const float* Wd    = (const float*)d_in[1];   // W_down  (16,256)
  const float* W2    = (const float*)d_in[2];   // W_down2 (256,256)
  const float* K1w   = (const float*)d_in[3];
  const float* K2w   = (const float*)d_in[4];
  const float* K3w   = (const float*)d_in[5];
  const float* Wb    = (const float*)d_in[6];   // W_back (256,16)
  const float* wts   = (const float*)d_in[7];   // weights (3)
  const float* w2arr = (const float*)d_in[8];   // weights2 (6)
  // d_in[9] = weights3 unused by the reference forward

  float* ws  = (float*)d_ws;
  float* x2  = ws;                                  // B*C*T*HW floats
  float* xr  = x2 + (size_t)B_*C_*T_*HW_;           // B*RC*T*HW floats
  float* agg = xr + (size_t)B_*RC_*T_*HW_;          // B*RC*T*HW floats
  float* out = (float*)d_out;

  k1_pointwise<<<dim3(HW_/K1_PT, B_*T_), 256, 0, stream>>>(x, W2, Wd, x2, xr);
  k2_dwconv  <<<dim3(T_, B_*RC_),        256, 0, stream>>>(xr, K1w, K2w, K3w, wts, agg);
  k3_attn    <<<dim3(HW_/A_TM, B_*T_),   256, 0, stream>>>(x, x2, w2arr, out);
  k4_gate    <<<dim3(HW_/K4_PT, B_*T_),  256, 0, stream>>>(agg, Wb, out);
}

// Round 3
// 563.505 us; speedup vs baseline: 4.0942x; 4.0942x over previous
//
#include <hip/hip_runtime.h>
#include <math.h>

#define B_ 2
#define C_ 256
#define T_ 16
#define H_ 28
#define W_ 28
#define HW_ 784
#define RC_ 16
#define QP_ 832                      // padded key/pixel count (13*64)
#define CT_STRIDE (T_*HW_)

typedef __attribute__((ext_vector_type(8))) short bf16x8;
typedef __attribute__((ext_vector_type(4))) float f32x4;

__device__ __forceinline__ f32x4 mfma16(bf16x8 a, bf16x8 b, f32x4 c) {
  return __builtin_amdgcn_mfma_f32_16x16x32_bf16(a, b, c, 0, 0, 0);
}
__device__ __forceinline__ unsigned short f2bf(float f) {
  unsigned u = __float_as_uint(f);
  unsigned r = (u + 0x7FFFu + ((u >> 16) & 1u)) >> 16;   // RNE
  return (unsigned short)r;
}
__device__ __forceinline__ float bf2f(unsigned short h) {
  return __uint_as_float((unsigned)h << 16);
}

// ---------------- k0: zero the q-pad regions (784..831) of x2 bf16 buffers -------------
__global__ __launch_bounds__(256) void k0_zero(
    unsigned short* __restrict__ x2t_h, unsigned short* __restrict__ x2t_l,
    unsigned short* __restrict__ x2c_h)
{
  int i = blockIdx.x * 256 + threadIdx.x;           // 0 .. 393215
  if (i >= 2*16*48*256) return;
  // x2t pads: [b*t][q=784..831][c]
  int bt  = i / (48*256);
  int rem = i - bt*(48*256);
  int q   = 784 + rem / 256;
  int c   = rem & 255;
  size_t off = ((size_t)bt*QP_ + q)*C_ + c;
  x2t_h[off] = 0; x2t_l[off] = 0;
  // x2c pads: [b*c*t][q=784..831]
  int bct = i / 48;
  int qq  = 784 + (i - bct*48);
  x2c_h[(size_t)bct*QP_ + qq] = 0;
}

// ---------------- k1: pointwise convs; writes x2 (bf16 hi/lo, two layouts) + xr f32 ----
#define K1_PT 28
__global__ __launch_bounds__(256) void k1_pointwise(
    const float* __restrict__ x, const float* __restrict__ W2,
    const float* __restrict__ Wd, unsigned short* __restrict__ x2t_h,
    unsigned short* __restrict__ x2t_l, unsigned short* __restrict__ x2c_h,
    float* __restrict__ xr)
{
  __shared__ float Xls[C_][K1_PT];
  __shared__ unsigned int Xt[K1_PT][260];   // packed (lo<<16)|hi per (p, out-c)
  const int tid = threadIdx.x;
  const int bt  = blockIdx.y;
  const int b = bt >> 4, t = bt & 15;
  const int p0 = blockIdx.x * K1_PT;
  const float* xbase = x + ((size_t)b*C_*T_ + t)*HW_ + p0;
  for (int idx = tid; idx < C_*K1_PT; idx += 256) {
    int c = idx / K1_PT, p = idx - c*K1_PT;
    Xls[c][p] = xbase[(size_t)c*CT_STRIDE + p];
  }
  __syncthreads();
  const int o = tid;
  float acc[K1_PT];
  #pragma unroll
  for (int p = 0; p < K1_PT; ++p) acc[p] = 0.f;
  const float* wrow = W2 + o*C_;
  for (int c0 = 0; c0 < C_; c0 += 8) {
    float4 wA = *(const float4*)(wrow + c0);
    float4 wB = *(const float4*)(wrow + c0 + 4);
    float wv[8] = {wA.x, wA.y, wA.z, wA.w, wB.x, wB.y, wB.z, wB.w};
    #pragma unroll
    for (int cc = 0; cc < 8; ++cc) {
      #pragma unroll
      for (int p = 0; p < K1_PT; ++p)
        acc[p] += wv[cc] * Xls[c0+cc][p];
    }
  }
  // natural-layout bf16 (V for PV)
  {
    size_t cb = (((size_t)b*C_ + o)*T_ + t)*QP_ + p0;
    #pragma unroll
    for (int p = 0; p < K1_PT; ++p) x2c_h[cb + p] = f2bf(acc[p]);
  }
  // pack hi/lo for transposed layout
  #pragma unroll
  for (int p = 0; p < K1_PT; ++p) {
    unsigned h = f2bf(acc[p]);
    unsigned l = f2bf(acc[p] - bf2f((unsigned short)h));
    Xt[p][o] = h | (l << 16);
  }
  // xr: RC_ x K1_PT outputs per block (reads Xls; before the transpose sync)
  for (int e = tid; e < RC_*K1_PT; e += 256) {
    int r = e / K1_PT, p = e - r*K1_PT;
    const float* wdr = Wd + r*C_;
    float a = 0.f;
    for (int c0 = 0; c0 < C_; c0 += 4) {
      float4 wv4 = *(const float4*)(wdr + c0);
      a += wv4.x*Xls[c0][p] + wv4.y*Xls[c0+1][p] + wv4.z*Xls[c0+2][p] + wv4.w*Xls[c0+3][p];
    }
    xr[((size_t)(b*RC_ + r)*T_ + t)*HW_ + p0 + p] = a;
  }
  __syncthreads();
  // transposed writes: x2t[b][t][p][c], c-contiguous, paired u32
  const size_t tb = (((size_t)b*T_ + t)*QP_ + p0)*C_;
  for (int idx = tid; idx < K1_PT*128; idx += 256) {
    int p = idx >> 7, cp = (idx & 127) * 2;
    unsigned a  = Xt[p][cp];
    unsigned b2 = Xt[p][cp+1];
    *(unsigned*)(x2t_h + tb + (size_t)p*C_ + cp) = (a & 0xFFFFu) | (b2 << 16);
    *(unsigned*)(x2t_l + tb + (size_t)p*C_ + cp) = (a >> 16) | (b2 & 0xFFFF0000u);
  }
}

// ---------------- k2: 3x dilated depthwise 3D conv on xr, combined (unchanged) ---------
__global__ __launch_bounds__(256) void k2_dwconv(
    const float* __restrict__ xr, const float* __restrict__ K1w,
    const float* __restrict__ K2w, const float* __restrict__ K3w,
    const float* __restrict__ wts, float* __restrict__ agg)
{
  __shared__ float slab[9][HW_];
  __shared__ float kw[3][81];
  const int tid = threadIdx.x;
  const int t  = blockIdx.x;
  const int br = blockIdx.y;
  const int r = br & 15;
  const size_t chbase = (size_t)br * T_ * HW_;
  for (int idx = tid; idx < 9*HW_; idx += 256) {
    int kd = idx / HW_, pp = idx - kd*HW_;
    int tt = t + kd - 4;
    slab[kd][pp] = (tt >= 0 && tt < T_) ? xr[chbase + (size_t)tt*HW_ + pp] : 0.f;
  }
  for (int idx = tid; idx < 3*81; idx += 256) {
    int kk = idx / 81, rem = idx - kk*81;
    const float* Ksrc = (kk == 0) ? K1w : ((kk == 1) ? K2w : K3w);
    kw[kk][rem] = Ksrc[r*81 + rem];
  }
  __syncthreads();
  const float w0 = wts[0], w1 = wts[1], w2v = wts[2];
  for (int p = tid; p < HW_; p += 256) {
    int h = p / W_, w = p - h*W_;
    float s0 = 0.f, s1 = 0.f, s2 = 0.f;
    for (int kd = 0; kd < 9; ++kd) {
      #pragma unroll
      for (int kh = 0; kh < 3; ++kh) {
        #pragma unroll
        for (int kwi = 0; kwi < 3; ++kwi) {
          const int widx = kd*9 + kh*3 + kwi;
          { int hh = h + (kh-1), ww = w + (kwi-1);
            if (hh >= 0 && hh < H_ && ww >= 0 && ww < W_)
              s0 += kw[0][widx] * slab[kd][hh*W_ + ww]; }
          { int hh = h + (kh-1)*2, ww = w + (kwi-1)*2;
            if (hh >= 0 && hh < H_ && ww >= 0 && ww < W_)
              s1 += kw[1][widx] * slab[kd][hh*W_ + ww]; }
          { int hh = h + (kh-1)*3, ww = w + (kwi-1)*3;
            if (hh >= 0 && hh < H_ && ww >= 0 && ww < W_)
              s2 += kw[2][widx] * slab[kd][hh*W_ + ww]; }
        }
      }
    }
    agg[chbase + (size_t)t*HW_ + p] = w0*s0 + w1*s1 + w2v*s2;
  }
}

// ---------------- k3: MFMA sigmoid-attention, 3-pass hi/lo QK^T, bf16 PV ---------------
// Block: 32 queries (2 m-tiles) for one (b,t). 4 waves: wave w owns key-subtile w*16 of
// each 64-key chunk for QK, and channel-quarter w*64 for PV. P via LDS; O in AGPRs.
__global__ __launch_bounds__(256, 2) void k3_attn_mfma(
    const float* __restrict__ x, const unsigned short* __restrict__ x2t_h,
    const unsigned short* __restrict__ x2t_l, const unsigned short* __restrict__ x2c_h,
    const float* __restrict__ w2arr, float* __restrict__ outF)
{
  __shared__ unsigned short Qh[32][264];   // [p][c], +8 pad: 2-way banks only
  __shared__ unsigned short Ql[32][264];
  __shared__ unsigned short Pls[32][72];   // [p][q-in-chunk], +8 pad
  const int tid  = threadIdx.x;
  const int lane = tid & 63, wv = tid >> 6;
  const int lm = lane & 15, lg = lane >> 4;
  const int bt = blockIdx.y;
  const int b = bt >> 4, t = bt & 15;
  const int p0 = blockIdx.x * 32;

  // ---- stage Q hi/lo into LDS (transpose from x [c][p] to [p][c]) ----
  {
    const int c = tid;
    const float* xp = x + (((size_t)b*C_ + c)*T_ + t)*HW_ + p0;
    for (int p4 = 0; p4 < 32; p4 += 4) {
      float4 v;
      if (p0 + p4 + 3 < HW_) v = *(const float4*)(xp + p4);
      else { v.x = 0.f; v.y = 0.f; v.z = 0.f; v.w = 0.f; }
      float vv[4] = {v.x, v.y, v.z, v.w};
      #pragma unroll
      for (int j = 0; j < 4; ++j) {
        unsigned short h = f2bf(vv[j]);
        Qh[p4+j][c] = h;
        Ql[p4+j][c] = f2bf(vv[j] - bf2f(h));
      }
    }
  }
  __syncthreads();

  // ---- persistent Qh fragments: [2 p-tiles][8 k-steps] = 64 VGPRs ----
  bf16x8 qh[2][8];
  #pragma unroll
  for (int pt = 0; pt < 2; ++pt)
    #pragma unroll
    for (int kk = 0; kk < 8; ++kk)
      qh[pt][kk] = *(const bf16x8*)&Qh[pt*16 + lm][kk*32 + lg*8];

  f32x4 O[4][2];
  #pragma unroll
  for (int mt = 0; mt < 4; ++mt)
    #pragma unroll
    for (int nt = 0; nt < 2; ++nt)
      O[mt][nt] = (f32x4){0.f, 0.f, 0.f, 0.f};

  const float wd0 = w2arr[0], wd1 = w2arr[1];

  for (int dir = 0; dir < 2; ++dir) {
    const int ts = (dir == 0) ? (t < T_-1 ? t+1 : T_-1) : (t > 0 ? t-1 : 0);
    const float wdir = (dir == 0) ? wd0 : wd1;
    const size_t kf = ((size_t)b*T_ + ts)*QP_;        // x2t frame row base (in q units)

    for (int ch = 0; ch < 13; ++ch) {
      const int q0 = ch * 64;
      const int qw = q0 + wv*16 + lm;                 // this lane's key row
      const unsigned short* khp = x2t_h + (kf + qw)*C_ + lg*8;
      const unsigned short* klp = x2t_l + (kf + qw)*C_ + lg*8;

      f32x4 S0 = {0.f,0.f,0.f,0.f}, S1 = {0.f,0.f,0.f,0.f};
      bf16x8 kh[8];
      #pragma unroll
      for (int kk = 0; kk < 8; ++kk) {                // pass 1: Qh*Kh (Kh kept)
        kh[kk] = *(const bf16x8*)(khp + kk*32);
        S0 = mfma16(qh[0][kk], kh[kk], S0);
        S1 = mfma16(qh[1][kk], kh[kk], S1);
      }
      #pragma unroll
      for (int kk = 0; kk < 8; ++kk) {                // pass 2: Ql*Kh
        bf16x8 ql0 = *(const bf16x8*)&Ql[lm][kk*32 + lg*8];
        bf16x8 ql1 = *(const bf16x8*)&Ql[16 + lm][kk*32 + lg*8];
        S0 = mfma16(ql0, kh[kk], S0);
        S1 = mfma16(ql1, kh[kk], S1);
      }
      #pragma unroll
      for (int kk = 0; kk < 8; ++kk) {                // pass 3: Qh*Kl (Kl streamed)
        bf16x8 kl = *(const bf16x8*)(klp + kk*32);
        S0 = mfma16(qh[0][kk], kl, S0);
        S1 = mfma16(qh[1][kk], kl, S1);
      }
      // sigmoid -> P (bf16) ; acc layout: row=(lg*4+r), col=lm
      #pragma unroll
      for (int r = 0; r < 4; ++r) {
        float pa = wdir * (1.f / (1.f + __expf(-S0[r])) - 0.5f);
        float pb = wdir * (1.f / (1.f + __expf(-S1[r])) - 0.5f);
        Pls[lg*4 + r][wv*16 + lm]      = f2bf(pa);
        Pls[16 + lg*4 + r][wv*16 + lm] = f2bf(pb);
      }
      __syncthreads();
      // PV: wave's channel-quarter, contraction over the 64-key chunk
      bf16x8 pbf[2][2];
      #pragma unroll
      for (int nt = 0; nt < 2; ++nt)
        #pragma unroll
        for (int ks = 0; ks < 2; ++ks)
          pbf[nt][ks] = *(const bf16x8*)&Pls[nt*16 + lm][ks*32 + lg*8];
      #pragma unroll
      for (int mt = 0; mt < 4; ++mt) {
        const int c = wv*64 + mt*16 + lm;
        const unsigned short* vb = x2c_h + (((size_t)b*C_ + c)*T_ + ts)*QP_ + q0 + lg*8;
        #pragma unroll
        for (int ks = 0; ks < 2; ++ks) {
          bf16x8 va = *(const bf16x8*)(vb + ks*32);
          O[mt][0] = mfma16(va, pbf[0][ks], O[mt][0]);
          O[mt][1] = mfma16(va, pbf[1][ks], O[mt][1]);
        }
      }
      __syncthreads();                                 // P reuse guard
    }
  }
  // ---- epilogue: O[c][p] -> out ----
  #pragma unroll
  for (int mt = 0; mt < 4; ++mt) {
    const int cbase = wv*64 + mt*16 + lg*4;
    #pragma unroll
    for (int nt = 0; nt < 2; ++nt) {
      const int p = p0 + nt*16 + lm;
      if (p < HW_) {
        #pragma unroll
        for (int r = 0; r < 4; ++r)
          outF[(((size_t)b*C_ + (cbase + r))*T_ + t)*HW_ + p] = O[mt][nt][r];
      }
    }
  }
}

// ---------------- k4: gate = sigma(W_back @ agg) - 0.5 ; out *= gate (unchanged) -------
#define K4_PT 112
__global__ __launch_bounds__(256) void k4_gate(
    const float* __restrict__ agg, const float* __restrict__ Wb,
    float* __restrict__ out)
{
  __shared__ float aggl[RC_][K4_PT];
  const int tid = threadIdx.x;
  const int bt  = blockIdx.y;
  const int b = bt >> 4, t = bt & 15;
  const int p0 = blockIdx.x * K4_PT;
  for (int idx = tid; idx < RC_*K4_PT; idx += 256) {
    int r = idx / K4_PT, p = idx - r*K4_PT;
    aggl[r][p] = agg[((size_t)(b*RC_ + r)*T_ + t)*HW_ + p0 + p];
  }
  __syncthreads();
  const int o = tid;
  float wb[RC_];
  #pragma unroll
  for (int r4 = 0; r4 < RC_; r4 += 4) {
    float4 v = *(const float4*)(Wb + o*RC_ + r4);
    wb[r4] = v.x; wb[r4+1] = v.y; wb[r4+2] = v.z; wb[r4+3] = v.w;
  }
  float* orow = out + ((size_t)(b*C_ + o)*T_ + t)*HW_ + p0;
  for (int p = 0; p < K4_PT; ++p) {
    float g = 0.f;
    #pragma unroll
    for (int r = 0; r < RC_; ++r) g += wb[r] * aggl[r][p];
    float sig = 1.f / (1.f + __expf(-g));
    orow[p] *= (sig - 0.5f);
  }
}

extern "C" void kernel_launch(void* const* d_in, const int* in_sizes, int n_in,
                              void* d_out, int out_size, void* d_ws, size_t ws_size,
                              hipStream_t stream)
{
  const float* x     = (const float*)d_in[0];
  const float* Wd    = (const float*)d_in[1];   // W_down  (16,256)
  const float* W2    = (const float*)d_in[2];   // W_down2 (256,256)
  const float* K1w   = (const float*)d_in[3];
  const float* K2w   = (const float*)d_in[4];
  const float* K3w   = (const float*)d_in[5];
  const float* Wb    = (const float*)d_in[6];   // W_back (256,16)
  const float* wts   = (const float*)d_in[7];   // weights (3)
  const float* w2arr = (const float*)d_in[8];   // weights2 (6)

  const size_t NX2T = (size_t)B_ * T_ * QP_ * C_;     // 6,815,744 elems
  unsigned short* x2t_h = (unsigned short*)d_ws;
  unsigned short* x2t_l = x2t_h + NX2T;
  unsigned short* x2c_h = x2t_l + NX2T;
  float* xr  = (float*)(x2c_h + NX2T);                // 401,408 f32
  float* agg = xr + (size_t)B_*RC_*T_*HW_;
  float* out = (float*)d_out;

  k0_zero     <<<1536, 256, 0, stream>>>(x2t_h, x2t_l, x2c_h);
  k1_pointwise<<<dim3(HW_/K1_PT, B_*T_), 256, 0, stream>>>(x, W2, Wd, x2t_h, x2t_l, x2c_h, xr);
  k2_dwconv   <<<dim3(T_, B_*RC_),       256, 0, stream>>>(xr, K1w, K2w, K3w, wts, agg);
  k3_attn_mfma<<<dim3(25, B_*T_),        256, 0, stream>>>(x, x2t_h, x2t_l, x2c_h, w2arr, out);
  k4_gate     <<<dim3(HW_/K4_PT, B_*T_), 256, 0, stream>>>(agg, Wb, out);
}

// Round 5
// 535.981 us; speedup vs baseline: 4.3045x; 1.0514x over previous
//
#include <hip/hip_runtime.h>
#include <math.h>

#define B_ 2
#define C_ 256
#define T_ 16
#define H_ 28
#define W_ 28
#define HW_ 784
#define RC_ 16
#define QP_ 832                      // padded key/pixel count (13*64)
#define CT_STRIDE (T_*HW_)

typedef __attribute__((ext_vector_type(8))) short bf16x8;
typedef __attribute__((ext_vector_type(4))) float f32x4;

__device__ __forceinline__ f32x4 mfma16(bf16x8 a, bf16x8 b, f32x4 c) {
  return __builtin_amdgcn_mfma_f32_16x16x32_bf16(a, b, c, 0, 0, 0);
}
__device__ __forceinline__ unsigned short f2bf(float f) {
  unsigned u = __float_as_uint(f);
  unsigned r = (u + 0x7FFFu + ((u >> 16) & 1u)) >> 16;   // RNE
  return (unsigned short)r;
}
__device__ __forceinline__ float bf2f(unsigned short h) {
  return __uint_as_float((unsigned)h << 16);
}
__device__ __forceinline__ void load8(bf16x8* dst, const unsigned short* p) {
  #pragma unroll
  for (int kk = 0; kk < 8; ++kk) dst[kk] = *(const bf16x8*)(p + kk*32);
}

// ---------------- k0: zero the q-pad regions (784..831) of x2 bf16 buffers -------------
__global__ __launch_bounds__(256) void k0_zero(
    unsigned short* __restrict__ x2t_h, unsigned short* __restrict__ x2t_l,
    unsigned short* __restrict__ x2c_h)
{
  int i = blockIdx.x * 256 + threadIdx.x;           // 0 .. 393215
  if (i >= 2*16*48*256) return;
  // x2t pads: [b*t][q=784..831][c]
  int bt  = i / (48*256);
  int rem = i - bt*(48*256);
  int q   = 784 + rem / 256;
  int c   = rem & 255;
  size_t off = ((size_t)bt*QP_ + q)*C_ + c;
  x2t_h[off] = 0; x2t_l[off] = 0;
  // x2c pads: [b*c*t][q=784..831]
  int bct = i / 48;
  int qq  = 784 + (i - bct*48);
  x2c_h[(size_t)bct*QP_ + qq] = 0;
}

// ---------------- k1: pointwise convs; writes x2 (bf16 hi/lo, two layouts) + xr f32 ----
#define K1_PT 28
__global__ __launch_bounds__(256) void k1_pointwise(
    const float* __restrict__ x, const float* __restrict__ W2,
    const float* __restrict__ Wd, unsigned short* __restrict__ x2t_h,
    unsigned short* __restrict__ x2t_l, unsigned short* __restrict__ x2c_h,
    float* __restrict__ xr)
{
  __shared__ float Xls[C_][K1_PT];
  __shared__ unsigned int Xt[K1_PT][260];   // packed (lo<<16)|hi per (p, out-c)
  const int tid = threadIdx.x;
  const int bt  = blockIdx.y;
  const int b = bt >> 4, t = bt & 15;
  const int p0 = blockIdx.x * K1_PT;
  const float* xbase = x + ((size_t)b*C_*T_ + t)*HW_ + p0;
  for (int idx = tid; idx < C_*K1_PT; idx += 256) {
    int c = idx / K1_PT, p = idx - c*K1_PT;
    Xls[c][p] = xbase[(size_t)c*CT_STRIDE + p];
  }
  __syncthreads();
  const int o = tid;
  float acc[K1_PT];
  #pragma unroll
  for (int p = 0; p < K1_PT; ++p) acc[p] = 0.f;
  const float* wrow = W2 + o*C_;
  for (int c0 = 0; c0 < C_; c0 += 8) {
    float4 wA = *(const float4*)(wrow + c0);
    float4 wB = *(const float4*)(wrow + c0 + 4);
    float wv[8] = {wA.x, wA.y, wA.z, wA.w, wB.x, wB.y, wB.z, wB.w};
    #pragma unroll
    for (int cc = 0; cc < 8; ++cc) {
      #pragma unroll
      for (int p = 0; p < K1_PT; ++p)
        acc[p] += wv[cc] * Xls[c0+cc][p];
    }
  }
  // natural-layout bf16 (V for PV)
  {
    size_t cb = (((size_t)b*C_ + o)*T_ + t)*QP_ + p0;
    #pragma unroll
    for (int p = 0; p < K1_PT; ++p) x2c_h[cb + p] = f2bf(acc[p]);
  }
  // pack hi/lo for transposed layout
  #pragma unroll
  for (int p = 0; p < K1_PT; ++p) {
    unsigned h = f2bf(acc[p]);
    unsigned l = f2bf(acc[p] - bf2f((unsigned short)h));
    Xt[p][o] = h | (l << 16);
  }
  // xr: RC_ x K1_PT outputs per block (reads Xls; before the transpose sync)
  for (int e = tid; e < RC_*K1_PT; e += 256) {
    int r = e / K1_PT, p = e - r*K1_PT;
    const float* wdr = Wd + r*C_;
    float a = 0.f;
    for (int c0 = 0; c0 < C_; c0 += 4) {
      float4 wv4 = *(const float4*)(wdr + c0);
      a += wv4.x*Xls[c0][p] + wv4.y*Xls[c0+1][p] + wv4.z*Xls[c0+2][p] + wv4.w*Xls[c0+3][p];
    }
    xr[((size_t)(b*RC_ + r)*T_ + t)*HW_ + p0 + p] = a;
  }
  __syncthreads();
  // transposed writes: x2t[b][t][p][c], c-contiguous, paired u32
  const size_t tb = (((size_t)b*T_ + t)*QP_ + p0)*C_;
  for (int idx = tid; idx < K1_PT*128; idx += 256) {
    int p = idx >> 7, cp = (idx & 127) * 2;
    unsigned a  = Xt[p][cp];
    unsigned b2 = Xt[p][cp+1];
    *(unsigned*)(x2t_h + tb + (size_t)p*C_ + cp) = (a & 0xFFFFu) | (b2 << 16);
    *(unsigned*)(x2t_l + tb + (size_t)p*C_ + cp) = (a >> 16) | (b2 & 0xFFFF0000u);
  }
}

// ---------------- k2: 3x dilated depthwise 3D conv on xr, combined (unchanged) ---------
__global__ __launch_bounds__(256) void k2_dwconv(
    const float* __restrict__ xr, const float* __restrict__ K1w,
    const float* __restrict__ K2w, const float* __restrict__ K3w,
    const float* __restrict__ wts, float* __restrict__ agg)
{
  __shared__ float slab[9][HW_];
  __shared__ float kw[3][81];
  const int tid = threadIdx.x;
  const int t  = blockIdx.x;
  const int br = blockIdx.y;
  const int r = br & 15;
  const size_t chbase = (size_t)br * T_ * HW_;
  for (int idx = tid; idx < 9*HW_; idx += 256) {
    int kd = idx / HW_, pp = idx - kd*HW_;
    int tt = t + kd - 4;
    slab[kd][pp] = (tt >= 0 && tt < T_) ? xr[chbase + (size_t)tt*HW_ + pp] : 0.f;
  }
  for (int idx = tid; idx < 3*81; idx += 256) {
    int kk = idx / 81, rem = idx - kk*81;
    const float* Ksrc = (kk == 0) ? K1w : ((kk == 1) ? K2w : K3w);
    kw[kk][rem] = Ksrc[r*81 + rem];
  }
  __syncthreads();
  const float w0 = wts[0], w1 = wts[1], w2v = wts[2];
  for (int p = tid; p < HW_; p += 256) {
    int h = p / W_, w = p - h*W_;
    float s0 = 0.f, s1 = 0.f, s2 = 0.f;
    for (int kd = 0; kd < 9; ++kd) {
      #pragma unroll
      for (int kh = 0; kh < 3; ++kh) {
        #pragma unroll
        for (int kwi = 0; kwi < 3; ++kwi) {
          const int widx = kd*9 + kh*3 + kwi;
          { int hh = h + (kh-1), ww = w + (kwi-1);
            if (hh >= 0 && hh < H_ && ww >= 0 && ww < W_)
              s0 += kw[0][widx] * slab[kd][hh*W_ + ww]; }
          { int hh = h + (kh-1)*2, ww = w + (kwi-1)*2;
            if (hh >= 0 && hh < H_ && ww >= 0 && ww < W_)
              s1 += kw[1][widx] * slab[kd][hh*W_ + ww]; }
          { int hh = h + (kh-1)*3, ww = w + (kwi-1)*3;
            if (hh >= 0 && hh < H_ && ww >= 0 && ww < W_)
              s2 += kw[2][widx] * slab[kd][hh*W_ + ww]; }
        }
      }
    }
    agg[chbase + (size_t)t*HW_ + p] = w0*s0 + w1*s1 + w2v*s2;
  }
}

// ---------------- k3: MFMA sigmoid-attention, pipelined, XCD-local, 1 barrier/chunk ----
// Block: 32 queries for one (b,t); 4 waves; wave w owns key-subtile w*16 of each 64-key
// chunk (QK) and channel-quarter w*64 (PV). P double-buffered in LDS, raw s_barrier.
// XCD swizzle: all 25 blocks of a frame (and 4 consecutive frames) land on one XCD.
#define CHUNK(KHC, KHN, CH, PB, PF)                                            \
{                                                                              \
  const unsigned short* klp = klp0 + (size_t)(CH)*64*C_;                       \
  bf16x8 kl[8];                                                                \
  load8(kl, klp);                              /* used in pass3 */             \
  f32x4 S0 = {0.f,0.f,0.f,0.f}, S1 = {0.f,0.f,0.f,0.f};                        \
  _Pragma("unroll")                                                            \
  for (int kk = 0; kk < 8; ++kk) {             /* pass 1: Qh*Kh */             \
    S0 = mfma16(qh[0][kk], KHC[kk], S0);                                       \
    S1 = mfma16(qh[1][kk], KHC[kk], S1);                                       \
  }                                                                            \
  _Pragma("unroll")                                                            \
  for (int kk = 0; kk < 8; ++kk) {             /* pass 2: Ql*Kh */             \
    bf16x8 ql0 = *(const bf16x8*)&Ql[lm][kk*32 + lg*8];                        \
    bf16x8 ql1 = *(const bf16x8*)&Ql[16 + lm][kk*32 + lg*8];                   \
    S0 = mfma16(ql0, KHC[kk], S0);                                             \
    S1 = mfma16(ql1, KHC[kk], S1);                                             \
  }                                                                            \
  bf16x8 vv[8];                                 /* hoisted V loads */          \
  _Pragma("unroll")                                                            \
  for (int mt = 0; mt < 4; ++mt) {                                             \
    vv[mt*2+0] = *(const bf16x8*)(vchunk0 + (size_t)mt*16*T_*QP_ + (size_t)(CH)*64);      \
    vv[mt*2+1] = *(const bf16x8*)(vchunk0 + (size_t)mt*16*T_*QP_ + (size_t)(CH)*64 + 32); \
  }                                                                            \
  if (PF) load8(KHN, khp0 + (size_t)((CH)+1)*64*C_);  /* next-chunk prefetch */\
  _Pragma("unroll")                                                            \
  for (int kk = 0; kk < 8; ++kk) {             /* pass 3: Qh*Kl */             \
    S0 = mfma16(qh[0][kk], kl[kk], S0);                                        \
    S1 = mfma16(qh[1][kk], kl[kk], S1);                                        \
  }                                                                            \
  _Pragma("unroll")                                                            \
  for (int r = 0; r < 4; ++r) {                /* sigmoid -> P bf16 */         \
    float pa = wdir * (1.f/(1.f+__expf(-S0[r])) - 0.5f);                       \
    float pb = wdir * (1.f/(1.f+__expf(-S1[r])) - 0.5f);                       \
    Pls[PB][lg*4+r][wv*16+lm]      = f2bf(pa);                                 \
    Pls[PB][16+lg*4+r][wv*16+lm]   = f2bf(pb);                                 \
  }                                                                            \
  __builtin_amdgcn_sched_barrier(0);                                           \
  asm volatile("s_waitcnt lgkmcnt(0)" ::: "memory");                           \
  __builtin_amdgcn_s_barrier();                                                \
  __builtin_amdgcn_sched_barrier(0);                                           \
  {                                                                            \
    bf16x8 pbf[2][2];                                                          \
    _Pragma("unroll")                                                          \
    for (int nt = 0; nt < 2; ++nt)                                             \
      _Pragma("unroll")                                                        \
      for (int ks = 0; ks < 2; ++ks)                                           \
        pbf[nt][ks] = *(const bf16x8*)&Pls[PB][nt*16+lm][ks*32+lg*8];          \
    _Pragma("unroll")                                                          \
    for (int mt = 0; mt < 4; ++mt) {                                           \
      _Pragma("unroll")                                                        \
      for (int ks = 0; ks < 2; ++ks) {                                         \
        O[mt][0] = mfma16(vv[mt*2+ks], pbf[0][ks], O[mt][0]);                  \
        O[mt][1] = mfma16(vv[mt*2+ks], pbf[1][ks], O[mt][1]);                  \
      }                                                                        \
    }                                                                          \
  }                                                                            \
}

__global__ __launch_bounds__(256, 2) void k3_attn_mfma(
    const float* __restrict__ x, const unsigned short* __restrict__ x2t_h,
    const unsigned short* __restrict__ x2t_l, const unsigned short* __restrict__ x2c_h,
    const float* __restrict__ w2arr, float* __restrict__ outF)
{
  __shared__ unsigned short Qh[32][264];   // [p][c], +8 pad
  __shared__ unsigned short Ql[32][264];
  __shared__ unsigned short Pls[2][32][72];
  const int tid  = threadIdx.x;
  const int lane = tid & 63, wv = tid >> 6;
  const int lm = lane & 15, lg = lane >> 4;
  // XCD-aware block swizzle (id%8 = XCD round-robin heuristic)
  const int id  = blockIdx.x;              // 0..799
  const int xcd = id & 7;
  const int j   = id >> 3;                 // 0..99
  const int frame = xcd*4 + (j/25);        // 0..31 ; 4 frames per XCD
  const int sub   = j - (j/25)*25;         // 0..24
  const int b = frame >> 4, t = frame & 15;
  const int p0 = sub * 32;

  // ---- stage Q hi/lo into LDS (transpose from x [c][p] to [p][c]) ----
  {
    const int c = tid;
    const float* xp = x + (((size_t)b*C_ + c)*T_ + t)*HW_ + p0;
    for (int p4 = 0; p4 < 32; p4 += 4) {
      float4 v;
      if (p0 + p4 + 3 < HW_) v = *(const float4*)(xp + p4);
      else { v.x = 0.f; v.y = 0.f; v.z = 0.f; v.w = 0.f; }
      float vvv[4] = {v.x, v.y, v.z, v.w};
      #pragma unroll
      for (int jj = 0; jj < 4; ++jj) {
        unsigned short h = f2bf(vvv[jj]);
        Qh[p4+jj][c] = h;
        Ql[p4+jj][c] = f2bf(vvv[jj] - bf2f(h));
      }
    }
  }
  __syncthreads();

  // ---- persistent Qh fragments: [2 p-tiles][8 k-steps] = 64 VGPRs ----
  bf16x8 qh[2][8];
  #pragma unroll
  for (int pt = 0; pt < 2; ++pt)
    #pragma unroll
    for (int kk = 0; kk < 8; ++kk)
      qh[pt][kk] = *(const bf16x8*)&Qh[pt*16 + lm][kk*32 + lg*8];

  f32x4 O[4][2];
  #pragma unroll
  for (int mt = 0; mt < 4; ++mt)
    #pragma unroll
    for (int nt = 0; nt < 2; ++nt)
      O[mt][nt] = (f32x4){0.f, 0.f, 0.f, 0.f};

  const float wd0 = w2arr[0], wd1 = w2arr[1];

  for (int dir = 0; dir < 2; ++dir) {
    const int ts = (dir == 0) ? (t < T_-1 ? t+1 : T_-1) : (t > 0 ? t-1 : 0);
    const float wdir = (dir == 0) ? wd0 : wd1;
    const size_t kf = ((size_t)b*T_ + ts)*QP_;
    const unsigned short* khp0 = x2t_h + (kf + wv*16 + lm)*C_ + lg*8;
    const unsigned short* klp0 = x2t_l + (kf + wv*16 + lm)*C_ + lg*8;
    const unsigned short* vchunk0 =
        x2c_h + (((size_t)b*C_ + wv*64 + lm)*T_ + ts)*QP_ + lg*8;

    bf16x8 khA[8], khB[8];
    load8(khA, khp0);                       // chunk-0 K_hi
    for (int cc = 0; cc < 6; ++cc) {
      CHUNK(khA, khB, (cc*2),   0, 1)
      CHUNK(khB, khA, (cc*2+1), 1, 1)
    }
    CHUNK(khA, khB, 12, 0, 0)
    __syncthreads();                         // P-buffer reuse guard across dirs
  }
  // ---- epilogue: O[c][p] -> out ----
  #pragma unroll
  for (int mt = 0; mt < 4; ++mt) {
    const int cbase = wv*64 + mt*16 + lg*4;
    #pragma unroll
    for (int nt = 0; nt < 2; ++nt) {
      const int p = p0 + nt*16 + lm;
      if (p < HW_) {
        #pragma unroll
        for (int r = 0; r < 4; ++r)
          outF[(((size_t)b*C_ + (cbase + r))*T_ + t)*HW_ + p] = O[mt][nt][r];
      }
    }
  }
}

// ---------------- k4: gate = sigma(W_back @ agg) - 0.5 ; out *= gate (unchanged) -------
#define K4_PT 112
__global__ __launch_bounds__(256) void k4_gate(
    const float* __restrict__ agg, const float* __restrict__ Wb,
    float* __restrict__ out)
{
  __shared__ float aggl[RC_][K4_PT];
  const int tid = threadIdx.x;
  const int bt  = blockIdx.y;
  const int b = bt >> 4, t = bt & 15;
  const int p0 = blockIdx.x * K4_PT;
  for (int idx = tid; idx < RC_*K4_PT; idx += 256) {
    int r = idx / K4_PT, p = idx - r*K4_PT;
    aggl[r][p] = agg[((size_t)(b*RC_ + r)*T_ + t)*HW_ + p0 + p];
  }
  __syncthreads();
  const int o = tid;
  float wb[RC_];
  #pragma unroll
  for (int r4 = 0; r4 < RC_; r4 += 4) {
    float4 v = *(const float4*)(Wb + o*RC_ + r4);
    wb[r4] = v.x; wb[r4+1] = v.y; wb[r4+2] = v.z; wb[r4+3] = v.w;
  }
  float* orow = out + ((size_t)(b*C_ + o)*T_ + t)*HW_ + p0;
  for (int p = 0; p < K4_PT; ++p) {
    float g = 0.f;
    #pragma unroll
    for (int r = 0; r < RC_; ++r) g += wb[r] * aggl[r][p];
    float sig = 1.f / (1.f + __expf(-g));
    orow[p] *= (sig - 0.5f);
  }
}

extern "C" void kernel_launch(void* const* d_in, const int* in_sizes, int n_in,
                              void* d_out, int out_size, void* d_ws, size_t ws_size,
                              hipStream_t stream)
{
  const float* x     = (const float*)d_in[0];
  const float* Wd    = (const float*)d_in[1];   // W_down  (16,256)
  const float* W2    = (const float*)d_in[2];   // W_down2 (256,256)
  const float* K1w   = (const float*)d_in[3];
  const float* K2w   = (const float*)d_in[4];
  const float* K3w   = (const float*)d_in[5];
  const float* Wb    = (const float*)d_in[6];   // W_back (256,16)
  const float* wts   = (const float*)d_in[7];   // weights (3)
  const float* w2arr = (const float*)d_in[8];   // weights2 (6)

  const size_t NX2T = (size_t)B_ * T_ * QP_ * C_;     // 6,815,744 elems
  unsigned short* x2t_h = (unsigned short*)d_ws;
  unsigned short* x2t_l = x2t_h + NX2T;
  unsigned short* x2c_h = x2t_l + NX2T;
  float* xr  = (float*)(x2c_h + NX2T);                // 401,408 f32
  float* agg = xr + (size_t)B_*RC_*T_*HW_;
  float* out = (float*)d_out;

  k0_zero     <<<1536, 256, 0, stream>>>(x2t_h, x2t_l, x2c_h);
  k1_pointwise<<<dim3(HW_/K1_PT, B_*T_), 256, 0, stream>>>(x, W2, Wd, x2t_h, x2t_l, x2c_h, xr);
  k2_dwconv   <<<dim3(T_, B_*RC_),       256, 0, stream>>>(xr, K1w, K2w, K3w, wts, agg);
  k3_attn_mfma<<<dim3(800),              256, 0, stream>>>(x, x2t_h, x2t_l, x2c_h, w2arr, out);
  k4_gate     <<<dim3(HW_/K4_PT, B_*T_), 256, 0, stream>>>(agg, Wb, out);
}

// Round 7
// 504.103 us; speedup vs baseline: 4.5767x; 1.0632x over previous
//
#include <hip/hip_runtime.h>
#include <math.h>

#define B_ 2
#define C_ 256
#define T_ 16
#define H_ 28
#define W_ 28
#define HW_ 784
#define RC_ 16
#define QP_ 832                      // padded key/pixel count (13*64)
#define CT_STRIDE (T_*HW_)

typedef __attribute__((ext_vector_type(8))) short bf16x8;
typedef __attribute__((ext_vector_type(4))) float f32x4;
typedef __attribute__((ext_vector_type(4))) unsigned short u16x4;

__device__ __forceinline__ f32x4 mfma16(bf16x8 a, bf16x8 b, f32x4 c) {
  return __builtin_amdgcn_mfma_f32_16x16x32_bf16(a, b, c, 0, 0, 0);
}
__device__ __forceinline__ unsigned short f2bf(float f) {
  unsigned u = __float_as_uint(f);
  unsigned r = (u + 0x7FFFu + ((u >> 16) & 1u)) >> 16;   // RNE
  return (unsigned short)r;
}
__device__ __forceinline__ float bf2f(unsigned short h) {
  return __uint_as_float((unsigned)h << 16);
}
__device__ __forceinline__ void load8(bf16x8* dst, const unsigned short* p) {
  #pragma unroll
  for (int kk = 0; kk < 8; ++kk) dst[kk] = *(const bf16x8*)(p + kk*32);
}
// shared XCD-aware swizzle for the 800-block frame kernels (k1, k3):
// all 25 blocks of a frame (and 4 consecutive frames) land on one XCD.
__device__ __forceinline__ void frame_swizzle(int id, int& b, int& t, int& p0) {
  const int xcd = id & 7;
  const int j   = id >> 3;                 // 0..99
  const int frame = xcd*4 + (j/25);        // 0..31
  const int sub   = j - (j/25)*25;         // 0..24
  b = frame >> 4; t = frame & 15; p0 = sub * 32;
}

// ---------------- k0: zero q-pads of x2 buffers + convert W2 -> bf16 hi/lo, Wd -> bf16 -
__global__ __launch_bounds__(256) void k0_prep(
    const float* __restrict__ W2, const float* __restrict__ Wd,
    unsigned short* __restrict__ x2t_h, unsigned short* __restrict__ x2t_l,
    unsigned short* __restrict__ x2c_h, unsigned short* __restrict__ W2h,
    unsigned short* __restrict__ W2l, unsigned short* __restrict__ Wdh)
{
  int i = blockIdx.x * 256 + threadIdx.x;
  if (i < 2*16*48*256) {
    // x2t pads: [b*t][q=784..831][c]
    int bt  = i / (48*256);
    int rem = i - bt*(48*256);
    int q   = 784 + rem / 256;
    int c   = rem & 255;
    size_t off = ((size_t)bt*QP_ + q)*C_ + c;
    x2t_h[off] = 0; x2t_l[off] = 0;
    // x2c pads: [b*c*t][q=784..831]
    int bct = i / 48;
    int qq  = 784 + (i - bct*48);
    x2c_h[(size_t)bct*QP_ + qq] = 0;
    return;
  }
  int j = i - 2*16*48*256;
  if (j < 65536) {
    float v = W2[j];
    unsigned short h = f2bf(v);
    W2h[j] = h; W2l[j] = f2bf(v - bf2f(h));
    return;
  }
  int k = j - 65536;
  if (k < 4096) Wdh[k] = f2bf(Wd[k]);
}

// ---------------- k1: MFMA pointwise convs: x2 = W2@x (3-pass hi/lo), xr = Wd@x --------
// Block: 32 p for one (b,t). x staged transposed hi/lo in LDS (like k3's Q).
// Wave wv owns output channels wv*64..wv*64+63 (4 o-tiles); wave 0 also does xr (16 ch).
__global__ __launch_bounds__(256, 2) void k1_mfma(
    const float* __restrict__ x, const unsigned short* __restrict__ W2h,
    const unsigned short* __restrict__ W2l, const unsigned short* __restrict__ Wdh,
    unsigned short* __restrict__ x2t_h, unsigned short* __restrict__ x2t_l,
    unsigned short* __restrict__ x2c_h, float* __restrict__ xr)
{
  __shared__ unsigned short Xth[32][266];   // odd dword-stride (133): <=2-way banks
  __shared__ unsigned short Xtl[32][266];
  const int tid  = threadIdx.x;
  const int lane = tid & 63, wv = tid >> 6;
  const int lm = lane & 15, lg = lane >> 4;
  int b, t, p0;
  frame_swizzle(blockIdx.x, b, t, p0);

  // stage x[c][p0..p0+31] -> Xt[p][c] hi/lo
  {
    const int c = tid;
    const float* xp = x + (((size_t)b*C_ + c)*T_ + t)*HW_ + p0;
    for (int p4 = 0; p4 < 32; p4 += 4) {
      float4 v;
      if (p0 + p4 + 3 < HW_) v = *(const float4*)(xp + p4);
      else { v.x = 0.f; v.y = 0.f; v.z = 0.f; v.w = 0.f; }
      float vv[4] = {v.x, v.y, v.z, v.w};
      #pragma unroll
      for (int jj = 0; jj < 4; ++jj) {
        unsigned short h = f2bf(vv[jj]);
        Xth[p4+jj][c] = h;
        Xtl[p4+jj][c] = f2bf(vv[jj] - bf2f(h));
      }
    }
  }
  __syncthreads();

  // B-fragments (x) in regs: [2 p-tiles][8 kk] hi/lo
  bf16x8 xh[2][8], xl[2][8];
  #pragma unroll
  for (int pt = 0; pt < 2; ++pt)
    #pragma unroll
    for (int kk = 0; kk < 8; ++kk) {
      xh[pt][kk] = *(const bf16x8*)&Xth[pt*16 + lm][kk*32 + lg*8];
      xl[pt][kk] = *(const bf16x8*)&Xtl[pt*16 + lm][kk*32 + lg*8];
    }

  const size_t tb = ((size_t)(b*T_ + t)*QP_);   // x2t frame base (q rows)
  #pragma unroll
  for (int m = 0; m < 4; ++m) {
    const int o0 = wv*64 + m*16;
    bf16x8 ah[8], al[8];
    load8(ah, W2h + (size_t)(o0 + lm)*C_ + lg*8);
    load8(al, W2l + (size_t)(o0 + lm)*C_ + lg*8);
    f32x4 a0 = {0.f,0.f,0.f,0.f}, a1 = {0.f,0.f,0.f,0.f};
    #pragma unroll
    for (int kk = 0; kk < 8; ++kk) { a0 = mfma16(ah[kk], xh[0][kk], a0); a1 = mfma16(ah[kk], xh[1][kk], a1); }
    #pragma unroll
    for (int kk = 0; kk < 8; ++kk) { a0 = mfma16(al[kk], xh[0][kk], a0); a1 = mfma16(al[kk], xh[1][kk], a1); }
    #pragma unroll
    for (int kk = 0; kk < 8; ++kk) { a0 = mfma16(ah[kk], xl[0][kk], a0); a1 = mfma16(ah[kk], xl[1][kk], a1); }
    // epilogue: D[o=(lg,r)][p=lm]
    #pragma unroll
    for (int pt = 0; pt < 2; ++pt) {
      f32x4 a = pt ? a1 : a0;
      const int p = p0 + pt*16 + lm;
      u16x4 hs, ls;
      #pragma unroll
      for (int r = 0; r < 4; ++r) {
        float v = a[r];
        unsigned short h = f2bf(v);
        hs[r] = h; ls[r] = f2bf(v - bf2f(h));
      }
      const size_t rowb = (tb + p)*C_ + o0 + lg*4;
      *(u16x4*)&x2t_h[rowb] = hs;
      *(u16x4*)&x2t_l[rowb] = ls;
      #pragma unroll
      for (int r = 0; r < 4; ++r) {
        const int c2 = o0 + lg*4 + r;
        x2c_h[(((size_t)b*C_ + c2)*T_ + t)*QP_ + p] = hs[r];
      }
    }
  }
  // xr = Wd @ x (2-pass: Wdh*xh + Wdh*xl), wave 0 only
  if (wv == 0) {
    bf16x8 ad[8];
    load8(ad, Wdh + (size_t)lm*C_ + lg*8);
    f32x4 r0 = {0.f,0.f,0.f,0.f}, r1 = {0.f,0.f,0.f,0.f};
    #pragma unroll
    for (int kk = 0; kk < 8; ++kk) { r0 = mfma16(ad[kk], xh[0][kk], r0); r1 = mfma16(ad[kk], xh[1][kk], r1); }
    #pragma unroll
    for (int kk = 0; kk < 8; ++kk) { r0 = mfma16(ad[kk], xl[0][kk], r0); r1 = mfma16(ad[kk], xl[1][kk], r1); }
    #pragma unroll
    for (int pt = 0; pt < 2; ++pt) {
      const int p = p0 + pt*16 + lm;
      if (p < HW_) {
        f32x4 rr = pt ? r1 : r0;
        #pragma unroll
        for (int r = 0; r < 4; ++r)
          xr[((size_t)(b*RC_ + lg*4 + r)*T_ + t)*HW_ + p] = rr[r];
      }
    }
  }
}

// ---------------- k2: 3x dilated depthwise 3D conv on xr, combined (unchanged) ---------
__global__ __launch_bounds__(256) void k2_dwconv(
    const float* __restrict__ xr, const float* __restrict__ K1w,
    const float* __restrict__ K2w, const float* __restrict__ K3w,
    const float* __restrict__ wts, float* __restrict__ agg)
{
  __shared__ float slab[9][HW_];
  __shared__ float kw[3][81];
  const int tid = threadIdx.x;
  const int t  = blockIdx.x;
  const int br = blockIdx.y;
  const int r = br & 15;
  const size_t chbase = (size_t)br * T_ * HW_;
  for (int idx = tid; idx < 9*HW_; idx += 256) {
    int kd = idx / HW_, pp = idx - kd*HW_;
    int tt = t + kd - 4;
    slab[kd][pp] = (tt >= 0 && tt < T_) ? xr[chbase + (size_t)tt*HW_ + pp] : 0.f;
  }
  for (int idx = tid; idx < 3*81; idx += 256) {
    int kk = idx / 81, rem = idx - kk*81;
    const float* Ksrc = (kk == 0) ? K1w : ((kk == 1) ? K2w : K3w);
    kw[kk][rem] = Ksrc[r*81 + rem];
  }
  __syncthreads();
  const float w0 = wts[0], w1 = wts[1], w2v = wts[2];
  for (int p = tid; p < HW_; p += 256) {
    int h = p / W_, w = p - h*W_;
    float s0 = 0.f, s1 = 0.f, s2 = 0.f;
    for (int kd = 0; kd < 9; ++kd) {
      #pragma unroll
      for (int kh = 0; kh < 3; ++kh) {
        #pragma unroll
        for (int kwi = 0; kwi < 3; ++kwi) {
          const int widx = kd*9 + kh*3 + kwi;
          { int hh = h + (kh-1), ww = w + (kwi-1);
            if (hh >= 0 && hh < H_ && ww >= 0 && ww < W_)
              s0 += kw[0][widx] * slab[kd][hh*W_ + ww]; }
          { int hh = h + (kh-1)*2, ww = w + (kwi-1)*2;
            if (hh >= 0 && hh < H_ && ww >= 0 && ww < W_)
              s1 += kw[1][widx] * slab[kd][hh*W_ + ww]; }
          { int hh = h + (kh-1)*3, ww = w + (kwi-1)*3;
            if (hh >= 0 && hh < H_ && ww >= 0 && ww < W_)
              s2 += kw[2][widx] * slab[kd][hh*W_ + ww]; }
        }
      }
    }
    agg[chbase + (size_t)t*HW_ + p] = w0*s0 + w1*s1 + w2v*s2;
  }
}

// ---------------- k3: MFMA sigmoid-attention; Q hi+lo in regs; fixed LDS padding -------
// Block: 32 queries for one (b,t); 4 waves; wave w owns key-subtile w*16 of each 64-key
// chunk (QK) and channel-quarter w*64 (PV). P double-buffered in LDS, raw s_barrier.
__global__ __launch_bounds__(256, 2) void k3_attn_mfma(
    const float* __restrict__ x, const unsigned short* __restrict__ x2t_h,
    const unsigned short* __restrict__ x2t_l, const unsigned short* __restrict__ x2c_h,
    const float* __restrict__ w2arr, float* __restrict__ outF)
{
  __shared__ unsigned short Qh[32][266];   // odd dword-stride: <=2-way banks
  __shared__ unsigned short Ql[32][266];
  __shared__ unsigned short Pls[2][32][74];
  const int tid  = threadIdx.x;
  const int lane = tid & 63, wv = tid >> 6;
  const int lm = lane & 15, lg = lane >> 4;
  int b, t, p0;
  frame_swizzle(blockIdx.x, b, t, p0);

  // ---- stage Q hi/lo into LDS (transpose from x [c][p] to [p][c]) ----
  {
    const int c = tid;
    const float* xp = x + (((size_t)b*C_ + c)*T_ + t)*HW_ + p0;
    for (int p4 = 0; p4 < 32; p4 += 4) {
      float4 v;
      if (p0 + p4 + 3 < HW_) v = *(const float4*)(xp + p4);
      else { v.x = 0.f; v.y = 0.f; v.z = 0.f; v.w = 0.f; }
      float vvv[4] = {v.x, v.y, v.z, v.w};
      #pragma unroll
      for (int jj = 0; jj < 4; ++jj) {
        unsigned short h = f2bf(vvv[jj]);
        Qh[p4+jj][c] = h;
        Ql[p4+jj][c] = f2bf(vvv[jj] - bf2f(h));
      }
    }
  }
  __syncthreads();

  // ---- persistent Q fragments hi+lo: 128 VGPRs (chunk-invariant!) ----
  bf16x8 qh[2][8], ql[2][8];
  #pragma unroll
  for (int pt = 0; pt < 2; ++pt)
    #pragma unroll
    for (int kk = 0; kk < 8; ++kk) {
      qh[pt][kk] = *(const bf16x8*)&Qh[pt*16 + lm][kk*32 + lg*8];
      ql[pt][kk] = *(const bf16x8*)&Ql[pt*16 + lm][kk*32 + lg*8];
    }

  f32x4 O[4][2];
  #pragma unroll
  for (int mt = 0; mt < 4; ++mt)
    #pragma unroll
    for (int nt = 0; nt < 2; ++nt)
      O[mt][nt] = (f32x4){0.f, 0.f, 0.f, 0.f};

  const float wd0 = w2arr[0], wd1 = w2arr[1];

  for (int dir = 0; dir < 2; ++dir) {
    const int ts = (dir == 0) ? (t < T_-1 ? t+1 : T_-1) : (t > 0 ? t-1 : 0);
    const float wdir = (dir == 0) ? wd0 : wd1;
    const size_t kf = ((size_t)b*T_ + ts)*QP_;
    const unsigned short* khp0 = x2t_h + (kf + wv*16 + lm)*C_ + lg*8;
    const unsigned short* klp0 = x2t_l + (kf + wv*16 + lm)*C_ + lg*8;
    const unsigned short* vchunk0 =
        x2c_h + (((size_t)b*C_ + wv*64 + lm)*T_ + ts)*QP_ + lg*8;

    for (int ch = 0; ch < 13; ++ch) {
      const unsigned short* khp = khp0 + (size_t)ch*64*C_;
      const unsigned short* klp = klp0 + (size_t)ch*64*C_;
      bf16x8 kh[8], kl[8];
      load8(kh, khp);
      load8(kl, klp);
      f32x4 S0 = {0.f,0.f,0.f,0.f}, S1 = {0.f,0.f,0.f,0.f};
      #pragma unroll
      for (int kk = 0; kk < 8; ++kk) {             // pass 1: Qh*Kh
        S0 = mfma16(qh[0][kk], kh[kk], S0);
        S1 = mfma16(qh[1][kk], kh[kk], S1);
      }
      #pragma unroll
      for (int kk = 0; kk < 8; ++kk) {             // pass 2: Ql*Kh (regs only)
        S0 = mfma16(ql[0][kk], kh[kk], S0);
        S1 = mfma16(ql[1][kk], kh[kk], S1);
      }
      bf16x8 vv[8];                                 // V loads (reuse kh's reg window)
      #pragma unroll
      for (int mt = 0; mt < 4; ++mt) {
        vv[mt*2+0] = *(const bf16x8*)(vchunk0 + (size_t)mt*16*T_*QP_ + (size_t)ch*64);
        vv[mt*2+1] = *(const bf16x8*)(vchunk0 + (size_t)mt*16*T_*QP_ + (size_t)ch*64 + 32);
      }
      #pragma unroll
      for (int kk = 0; kk < 8; ++kk) {             // pass 3: Qh*Kl
        S0 = mfma16(qh[0][kk], kl[kk], S0);
        S1 = mfma16(qh[1][kk], kl[kk], S1);
      }
      const int PB = ch & 1;
      #pragma unroll
      for (int r = 0; r < 4; ++r) {                // sigmoid -> P bf16
        float pa = wdir * (1.f/(1.f+__expf(-S0[r])) - 0.5f);
        float pb = wdir * (1.f/(1.f+__expf(-S1[r])) - 0.5f);
        Pls[PB][lg*4+r][wv*16+lm]    = f2bf(pa);
        Pls[PB][16+lg*4+r][wv*16+lm] = f2bf(pb);
      }
      __builtin_amdgcn_sched_barrier(0);
      asm volatile("s_waitcnt lgkmcnt(0)" ::: "memory");
      __builtin_amdgcn_s_barrier();
      __builtin_amdgcn_sched_barrier(0);
      bf16x8 pbf[2][2];
      #pragma unroll
      for (int nt = 0; nt < 2; ++nt)
        #pragma unroll
        for (int ks = 0; ks < 2; ++ks)
          pbf[nt][ks] = *(const bf16x8*)&Pls[PB][nt*16+lm][ks*32+lg*8];
      #pragma unroll
      for (int mt = 0; mt < 4; ++mt)
        #pragma unroll
        for (int ks = 0; ks < 2; ++ks) {
          O[mt][0] = mfma16(vv[mt*2+ks], pbf[0][ks], O[mt][0]);
          O[mt][1] = mfma16(vv[mt*2+ks], pbf[1][ks], O[mt][1]);
        }
    }
    __syncthreads();                               // P-buffer reuse guard across dirs
  }
  // ---- epilogue: O[c][p] -> out ----
  #pragma unroll
  for (int mt = 0; mt < 4; ++mt) {
    const int cbase = wv*64 + mt*16 + lg*4;
    #pragma unroll
    for (int nt = 0; nt < 2; ++nt) {
      const int p = p0 + nt*16 + lm;
      if (p < HW_) {
        #pragma unroll
        for (int r = 0; r < 4; ++r)
          outF[(((size_t)b*C_ + (cbase + r))*T_ + t)*HW_ + p] = O[mt][nt][r];
      }
    }
  }
}

// ---------------- k4: gate = sigma(W_back @ agg) - 0.5 ; out *= gate (unchanged) -------
#define K4_PT 112
__global__ __launch_bounds__(256) void k4_gate(
    const float* __restrict__ agg, const float* __restrict__ Wb,
    float* __restrict__ out)
{
  __shared__ float aggl[RC_][K4_PT];
  const int tid = threadIdx.x;
  const int bt  = blockIdx.y;
  const int b = bt >> 4, t = bt & 15;
  const int p0 = blockIdx.x * K4_PT;
  for (int idx = tid; idx < RC_*K4_PT; idx += 256) {
    int r = idx / K4_PT, p = idx - r*K4_PT;
    aggl[r][p] = agg[((size_t)(b*RC_ + r)*T_ + t)*HW_ + p0 + p];
  }
  __syncthreads();
  const int o = tid;
  float wb[RC_];
  #pragma unroll
  for (int r4 = 0; r4 < RC_; r4 += 4) {
    float4 v = *(const float4*)(Wb + o*RC_ + r4);
    wb[r4] = v.x; wb[r4+1] = v.y; wb[r4+2] = v.z; wb[r4+3] = v.w;
  }
  float* orow = out + ((size_t)(b*C_ + o)*T_ + t)*HW_ + p0;
  for (int p = 0; p < K4_PT; ++p) {
    float g = 0.f;
    #pragma unroll
    for (int r = 0; r < RC_; ++r) g += wb[r] * aggl[r][p];
    float sig = 1.f / (1.f + __expf(-g));
    orow[p] *= (sig - 0.5f);
  }
}

extern "C" void kernel_launch(void* const* d_in, const int* in_sizes, int n_in,
                              void* d_out, int out_size, void* d_ws, size_t ws_size,
                              hipStream_t stream)
{
  const float* x     = (const float*)d_in[0];
  const float* Wd    = (const float*)d_in[1];   // W_down  (16,256)
  const float* W2    = (const float*)d_in[2];   // W_down2 (256,256)
  const float* K1w   = (const float*)d_in[3];
  const float* K2w   = (const float*)d_in[4];
  const float* K3w   = (const float*)d_in[5];
  const float* Wb    = (const float*)d_in[6];   // W_back (256,16)
  const float* wts   = (const float*)d_in[7];   // weights (3)
  const float* w2arr = (const float*)d_in[8];   // weights2 (6)

  const size_t NX2T = (size_t)B_ * T_ * QP_ * C_;     // 6,815,744 elems
  unsigned short* x2t_h = (unsigned short*)d_ws;
  unsigned short* x2t_l = x2t_h + NX2T;
  unsigned short* x2c_h = x2t_l + NX2T;
  float* xr  = (float*)(x2c_h + NX2T);                // 401,408 f32
  float* agg = xr + (size_t)B_*RC_*T_*HW_;            // 401,408 f32
  unsigned short* W2h = (unsigned short*)(agg + (size_t)B_*RC_*T_*HW_);
  unsigned short* W2l = W2h + 65536;
  unsigned short* Wdh = W2l + 65536;
  float* out = (float*)d_out;

  k0_prep <<<1808, 256, 0, stream>>>(W2, Wd, x2t_h, x2t_l, x2c_h, W2h, W2l, Wdh);
  k1_mfma <<<dim3(800), 256, 0, stream>>>(x, W2h, W2l, Wdh, x2t_h, x2t_l, x2c_h, xr);
  k2_dwconv<<<dim3(T_, B_*RC_), 256, 0, stream>>>(xr, K1w, K2w, K3w, wts, agg);
  k3_attn_mfma<<<dim3(800), 256, 0, stream>>>(x, x2t_h, x2t_l, x2c_h, w2arr, out);
  k4_gate <<<dim3(HW_/K4_PT, B_*T_), 256, 0, stream>>>(agg, Wb, out);
}

// Round 9
// 409.427 us; speedup vs baseline: 5.6350x; 1.2312x over previous
//
#include <hip/hip_runtime.h>
#include <math.h>

#define B_ 2
#define C_ 256
#define T_ 16
#define H_ 28
#define W_ 28
#define HW_ 784
#define RC_ 16
#define QP_ 832                      // padded key/pixel count (13*64)
#define CT_STRIDE (T_*HW_)

typedef __attribute__((ext_vector_type(8))) short bf16x8;
typedef __attribute__((ext_vector_type(4))) float f32x4;
typedef __attribute__((ext_vector_type(4))) unsigned short u16x4;

__device__ __forceinline__ f32x4 mfma16(bf16x8 a, bf16x8 b, f32x4 c) {
  return __builtin_amdgcn_mfma_f32_16x16x32_bf16(a, b, c, 0, 0, 0);
}
__device__ __forceinline__ unsigned short f2bf(float f) {
  unsigned u = __float_as_uint(f);
  unsigned r = (u + 0x7FFFu + ((u >> 16) & 1u)) >> 16;   // RNE
  return (unsigned short)r;
}
__device__ __forceinline__ float bf2f(unsigned short h) {
  return __uint_as_float((unsigned)h << 16);
}
__device__ __forceinline__ void load8(bf16x8* dst, const unsigned short* p) {
  #pragma unroll
  for (int kk = 0; kk < 8; ++kk) dst[kk] = *(const bf16x8*)(p + kk*32);
}
__device__ __forceinline__ void loadV(bf16x8* dst, const unsigned short* v0, int ch) {
  #pragma unroll
  for (int mt = 0; mt < 4; ++mt) {
    dst[mt*2+0] = *(const bf16x8*)(v0 + (size_t)mt*16*T_*QP_ + (size_t)ch*64);
    dst[mt*2+1] = *(const bf16x8*)(v0 + (size_t)mt*16*T_*QP_ + (size_t)ch*64 + 32);
  }
}
// shared XCD-aware swizzle for the 800-block frame kernels (k1, k3):
// all 25 blocks of a frame (and 4 consecutive frames) land on one XCD.
__device__ __forceinline__ void frame_swizzle(int id, int& b, int& t, int& p0) {
  const int xcd = id & 7;
  const int j   = id >> 3;                 // 0..99
  const int frame = xcd*4 + (j/25);        // 0..31
  const int sub   = j - (j/25)*25;         // 0..24
  b = frame >> 4; t = frame & 15; p0 = sub * 32;
}

// ---------------- k0: zero q-pads of x2 buffers + convert W2 -> bf16 hi/lo, Wd -> bf16 -
__global__ __launch_bounds__(256) void k0_prep(
    const float* __restrict__ W2, const float* __restrict__ Wd,
    unsigned short* __restrict__ x2t_h, unsigned short* __restrict__ x2c_h,
    unsigned short* __restrict__ W2h, unsigned short* __restrict__ W2l,
    unsigned short* __restrict__ Wdh)
{
  int i = blockIdx.x * 256 + threadIdx.x;
  if (i < 2*16*48*256) {
    // x2t pads: [b*t][q=784..831][c]
    int bt  = i / (48*256);
    int rem = i - bt*(48*256);
    int q   = 784 + rem / 256;
    int c   = rem & 255;
    x2t_h[((size_t)bt*QP_ + q)*C_ + c] = 0;
    // x2c pads: [b*c*t][q=784..831]
    int bct = i / 48;
    int qq  = 784 + (i - bct*48);
    x2c_h[(size_t)bct*QP_ + qq] = 0;
    return;
  }
  int j = i - 2*16*48*256;
  if (j < 65536) {
    float v = W2[j];
    unsigned short h = f2bf(v);
    W2h[j] = h; W2l[j] = f2bf(v - bf2f(h));
    return;
  }
  int k = j - 65536;
  if (k < 4096) Wdh[k] = f2bf(Wd[k]);
}

// ---------------- k1: MFMA pointwise convs: x2 = W2@x (3-pass hi/lo), xr = Wd@x --------
// Block: 32 p for one (b,t). x staged transposed hi/lo in LDS (like k3's Q).
// Wave wv owns output channels wv*64..wv*64+63 (4 o-tiles); wave 0 also does xr (16 ch).
__global__ __launch_bounds__(256, 2) void k1_mfma(
    const float* __restrict__ x, const unsigned short* __restrict__ W2h,
    const unsigned short* __restrict__ W2l, const unsigned short* __restrict__ Wdh,
    unsigned short* __restrict__ x2t_h, unsigned short* __restrict__ x2c_h,
    float* __restrict__ xr)
{
  __shared__ unsigned short Xth[32][266];   // odd dword-stride (133): <=2-way banks
  __shared__ unsigned short Xtl[32][266];
  const int tid  = threadIdx.x;
  const int lane = tid & 63, wv = tid >> 6;
  const int lm = lane & 15, lg = lane >> 4;
  int b, t, p0;
  frame_swizzle(blockIdx.x, b, t, p0);

  // stage x[c][p0..p0+31] -> Xt[p][c] hi/lo
  {
    const int c = tid;
    const float* xp = x + (((size_t)b*C_ + c)*T_ + t)*HW_ + p0;
    for (int p4 = 0; p4 < 32; p4 += 4) {
      float4 v;
      if (p0 + p4 + 3 < HW_) v = *(const float4*)(xp + p4);
      else { v.x = 0.f; v.y = 0.f; v.z = 0.f; v.w = 0.f; }
      float vv[4] = {v.x, v.y, v.z, v.w};
      #pragma unroll
      for (int jj = 0; jj < 4; ++jj) {
        unsigned short h = f2bf(vv[jj]);
        Xth[p4+jj][c] = h;
        Xtl[p4+jj][c] = f2bf(vv[jj] - bf2f(h));
      }
    }
  }
  __syncthreads();

  // B-fragments (x) in regs: [2 p-tiles][8 kk] hi/lo
  bf16x8 xh[2][8], xl[2][8];
  #pragma unroll
  for (int pt = 0; pt < 2; ++pt)
    #pragma unroll
    for (int kk = 0; kk < 8; ++kk) {
      xh[pt][kk] = *(const bf16x8*)&Xth[pt*16 + lm][kk*32 + lg*8];
      xl[pt][kk] = *(const bf16x8*)&Xtl[pt*16 + lm][kk*32 + lg*8];
    }

  const size_t tb = ((size_t)(b*T_ + t)*QP_);   // x2t frame base (q rows)
  #pragma unroll
  for (int m = 0; m < 4; ++m) {
    const int o0 = wv*64 + m*16;
    bf16x8 ah[8], al[8];
    load8(ah, W2h + (size_t)(o0 + lm)*C_ + lg*8);
    load8(al, W2l + (size_t)(o0 + lm)*C_ + lg*8);
    f32x4 a0 = {0.f,0.f,0.f,0.f}, a1 = {0.f,0.f,0.f,0.f};
    #pragma unroll
    for (int kk = 0; kk < 8; ++kk) { a0 = mfma16(ah[kk], xh[0][kk], a0); a1 = mfma16(ah[kk], xh[1][kk], a1); }
    #pragma unroll
    for (int kk = 0; kk < 8; ++kk) { a0 = mfma16(al[kk], xh[0][kk], a0); a1 = mfma16(al[kk], xh[1][kk], a1); }
    #pragma unroll
    for (int kk = 0; kk < 8; ++kk) { a0 = mfma16(ah[kk], xl[0][kk], a0); a1 = mfma16(ah[kk], xl[1][kk], a1); }
    // epilogue: D[o=(lg,r)][p=lm]
    #pragma unroll
    for (int pt = 0; pt < 2; ++pt) {
      f32x4 a = pt ? a1 : a0;
      const int p = p0 + pt*16 + lm;
      u16x4 hs;
      #pragma unroll
      for (int r = 0; r < 4; ++r) hs[r] = f2bf(a[r]);
      const size_t rowb = (tb + p)*C_ + o0 + lg*4;
      *(u16x4*)&x2t_h[rowb] = hs;
      #pragma unroll
      for (int r = 0; r < 4; ++r) {
        const int c2 = o0 + lg*4 + r;
        x2c_h[(((size_t)b*C_ + c2)*T_ + t)*QP_ + p] = hs[r];
      }
    }
  }
  // xr = Wd @ x (2-pass: Wdh*xh + Wdh*xl), wave 0 only
  if (wv == 0) {
    bf16x8 ad[8];
    load8(ad, Wdh + (size_t)lm*C_ + lg*8);
    f32x4 r0 = {0.f,0.f,0.f,0.f}, r1 = {0.f,0.f,0.f,0.f};
    #pragma unroll
    for (int kk = 0; kk < 8; ++kk) { r0 = mfma16(ad[kk], xh[0][kk], r0); r1 = mfma16(ad[kk], xh[1][kk], r1); }
    #pragma unroll
    for (int kk = 0; kk < 8; ++kk) { r0 = mfma16(ad[kk], xl[0][kk], r0); r1 = mfma16(ad[kk], xl[1][kk], r1); }
    #pragma unroll
    for (int pt = 0; pt < 2; ++pt) {
      const int p = p0 + pt*16 + lm;
      if (p < HW_) {
        f32x4 rr = pt ? r1 : r0;
        #pragma unroll
        for (int r = 0; r < 4; ++r)
          xr[((size_t)(b*RC_ + lg*4 + r)*T_ + t)*HW_ + p] = rr[r];
      }
    }
  }
}

// ---------------- k2: 3x dilated depthwise 3D conv on xr, combined (unchanged) ---------
__global__ __launch_bounds__(256) void k2_dwconv(
    const float* __restrict__ xr, const float* __restrict__ K1w,
    const float* __restrict__ K2w, const float* __restrict__ K3w,
    const float* __restrict__ wts, float* __restrict__ agg)
{
  __shared__ float slab[9][HW_];
  __shared__ float kw[3][81];
  const int tid = threadIdx.x;
  const int t  = blockIdx.x;
  const int br = blockIdx.y;
  const int r = br & 15;
  const size_t chbase = (size_t)br * T_ * HW_;
  for (int idx = tid; idx < 9*HW_; idx += 256) {
    int kd = idx / HW_, pp = idx - kd*HW_;
    int tt = t + kd - 4;
    slab[kd][pp] = (tt >= 0 && tt < T_) ? xr[chbase + (size_t)tt*HW_ + pp] : 0.f;
  }
  for (int idx = tid; idx < 3*81; idx += 256) {
    int kk = idx / 81, rem = idx - kk*81;
    const float* Ksrc = (kk == 0) ? K1w : ((kk == 1) ? K2w : K3w);
    kw[kk][rem] = Ksrc[r*81 + rem];
  }
  __syncthreads();
  const float w0 = wts[0], w1 = wts[1], w2v = wts[2];
  for (int p = tid; p < HW_; p += 256) {
    int h = p / W_, w = p - h*W_;
    float s0 = 0.f, s1 = 0.f, s2 = 0.f;
    for (int kd = 0; kd < 9; ++kd) {
      #pragma unroll
      for (int kh = 0; kh < 3; ++kh) {
        #pragma unroll
        for (int kwi = 0; kwi < 3; ++kwi) {
          const int widx = kd*9 + kh*3 + kwi;
          { int hh = h + (kh-1), ww = w + (kwi-1);
            if (hh >= 0 && hh < H_ && ww >= 0 && ww < W_)
              s0 += kw[0][widx] * slab[kd][hh*W_ + ww]; }
          { int hh = h + (kh-1)*2, ww = w + (kwi-1)*2;
            if (hh >= 0 && hh < H_ && ww >= 0 && ww < W_)
              s1 += kw[1][widx] * slab[kd][hh*W_ + ww]; }
          { int hh = h + (kh-1)*3, ww = w + (kwi-1)*3;
            if (hh >= 0 && hh < H_ && ww >= 0 && ww < W_)
              s2 += kw[2][widx] * slab[kd][hh*W_ + ww]; }
        }
      }
    }
    agg[chbase + (size_t)t*HW_ + p] = w0*s0 + w1*s1 + w2v*s2;
  }
}

// ---------------- k3: MFMA sigmoid-attention, 2-pass QK^T, kh-dbuf pipeline ------------
// Block: 32 queries for one (b,t); 4 waves; wave w owns key-subtile w*16 of each 64-key
// chunk (QK) and channel-quarter w*64 (PV). qh in regs; ql via LDS (pass 2).
// Per chunk: issue vv(cur)+kh(next) first, then MFMA passes cover the latency.
#define CHUNK2(KH, KHN, CH, PB, PF)                                            \
{                                                                              \
  bf16x8 vv[8];                                                                \
  loadV(vv, vchunk0, (CH));                    /* V for THIS chunk: in flight */\
  if (PF) load8(KHN, khp0 + (size_t)((CH)+1)*64*C_);  /* next-chunk K_hi */    \
  f32x4 S0 = {0.f,0.f,0.f,0.f}, S1 = {0.f,0.f,0.f,0.f};                        \
  _Pragma("unroll")                                                            \
  for (int kk = 0; kk < 8; ++kk) {             /* pass 1: Qh*Kh */             \
    S0 = mfma16(qh[0][kk], KH[kk], S0);                                        \
    S1 = mfma16(qh[1][kk], KH[kk], S1);                                        \
  }                                                                            \
  _Pragma("unroll")                                                            \
  for (int kk = 0; kk < 8; ++kk) {             /* pass 2: Ql*Kh (LDS) */       \
    bf16x8 ql0 = *(const bf16x8*)&Ql[lm][kk*32 + lg*8];                        \
    bf16x8 ql1 = *(const bf16x8*)&Ql[16 + lm][kk*32 + lg*8];                   \
    S0 = mfma16(ql0, KH[kk], S0);                                              \
    S1 = mfma16(ql1, KH[kk], S1);                                              \
  }                                                                            \
  _Pragma("unroll")                                                            \
  for (int r = 0; r < 4; ++r) {                /* sigmoid -> P bf16 */         \
    float pa = wdir * (1.f/(1.f+__expf(-S0[r])) - 0.5f);                       \
    float pb = wdir * (1.f/(1.f+__expf(-S1[r])) - 0.5f);                       \
    Pls[PB][lg*4+r][wv*16+lm]    = f2bf(pa);                                   \
    Pls[PB][16+lg*4+r][wv*16+lm] = f2bf(pb);                                   \
  }                                                                            \
  __builtin_amdgcn_sched_barrier(0);                                           \
  asm volatile("s_waitcnt lgkmcnt(0)" ::: "memory");                           \
  __builtin_amdgcn_s_barrier();                                                \
  __builtin_amdgcn_sched_barrier(0);                                           \
  {                                                                            \
    bf16x8 pbf[2][2];                                                          \
    _Pragma("unroll")                                                          \
    for (int nt = 0; nt < 2; ++nt)                                             \
      _Pragma("unroll")                                                        \
      for (int ks = 0; ks < 2; ++ks)                                           \
        pbf[nt][ks] = *(const bf16x8*)&Pls[PB][nt*16+lm][ks*32+lg*8];          \
    _Pragma("unroll")                                                          \
    for (int mt = 0; mt < 4; ++mt) {                                           \
      _Pragma("unroll")                                                        \
      for (int ks = 0; ks < 2; ++ks) {                                         \
        O[mt][0] = mfma16(vv[mt*2+ks], pbf[0][ks], O[mt][0]);                  \
        O[mt][1] = mfma16(vv[mt*2+ks], pbf[1][ks], O[mt][1]);                  \
      }                                                                        \
    }                                                                          \
  }                                                                            \
}

__global__ __launch_bounds__(256, 2) void k3_attn_mfma(
    const float* __restrict__ x, const unsigned short* __restrict__ x2t_h,
    const unsigned short* __restrict__ x2c_h,
    const float* __restrict__ w2arr, float* __restrict__ outF)
{
  __shared__ unsigned short Qh[32][266];   // odd dword-stride: <=2-way banks
  __shared__ unsigned short Ql[32][266];
  __shared__ unsigned short Pls[2][32][74];
  const int tid  = threadIdx.x;
  const int lane = tid & 63, wv = tid >> 6;
  const int lm = lane & 15, lg = lane >> 4;
  int b, t, p0;
  frame_swizzle(blockIdx.x, b, t, p0);

  // ---- stage Q hi/lo into LDS (transpose from x [c][p] to [p][c]) ----
  {
    const int c = tid;
    const float* xp = x + (((size_t)b*C_ + c)*T_ + t)*HW_ + p0;
    for (int p4 = 0; p4 < 32; p4 += 4) {
      float4 v;
      if (p0 + p4 + 3 < HW_) v = *(const float4*)(xp + p4);
      else { v.x = 0.f; v.y = 0.f; v.z = 0.f; v.w = 0.f; }
      float vvv[4] = {v.x, v.y, v.z, v.w};
      #pragma unroll
      for (int jj = 0; jj < 4; ++jj) {
        unsigned short h = f2bf(vvv[jj]);
        Qh[p4+jj][c] = h;
        Ql[p4+jj][c] = f2bf(vvv[jj] - bf2f(h));
      }
    }
  }
  __syncthreads();

  // ---- persistent Qh fragments (64 VGPRs); Ql read from LDS per chunk ----
  bf16x8 qh[2][8];
  #pragma unroll
  for (int pt = 0; pt < 2; ++pt)
    #pragma unroll
    for (int kk = 0; kk < 8; ++kk)
      qh[pt][kk] = *(const bf16x8*)&Qh[pt*16 + lm][kk*32 + lg*8];

  f32x4 O[4][2];
  #pragma unroll
  for (int mt = 0; mt < 4; ++mt)
    #pragma unroll
    for (int nt = 0; nt < 2; ++nt)
      O[mt][nt] = (f32x4){0.f, 0.f, 0.f, 0.f};

  const float wd0 = w2arr[0], wd1 = w2arr[1];

  for (int dir = 0; dir < 2; ++dir) {
    const int ts = (dir == 0) ? (t < T_-1 ? t+1 : T_-1) : (t > 0 ? t-1 : 0);
    const float wdir = (dir == 0) ? wd0 : wd1;
    const size_t kf = ((size_t)b*T_ + ts)*QP_;
    const unsigned short* khp0 = x2t_h + (kf + wv*16 + lm)*C_ + lg*8;
    const unsigned short* vchunk0 =
        x2c_h + (((size_t)b*C_ + wv*64 + lm)*T_ + ts)*QP_ + lg*8;

    bf16x8 khA[8], khB[8];
    load8(khA, khp0);                       // chunk-0 K_hi
    for (int cc = 0; cc < 6; ++cc) {
      CHUNK2(khA, khB, (cc*2),   0, 1)
      CHUNK2(khB, khA, (cc*2+1), 1, 1)
    }
    CHUNK2(khA, khB, 12, 0, 0)
    __syncthreads();                         // P-buffer reuse guard across dirs
  }
  // ---- epilogue: O[c][p] -> out ----
  #pragma unroll
  for (int mt = 0; mt < 4; ++mt) {
    const int cbase = wv*64 + mt*16 + lg*4;
    #pragma unroll
    for (int nt = 0; nt < 2; ++nt) {
      const int p = p0 + nt*16 + lm;
      if (p < HW_) {
        #pragma unroll
        for (int r = 0; r < 4; ++r)
          outF[(((size_t)b*C_ + (cbase + r))*T_ + t)*HW_ + p] = O[mt][nt][r];
      }
    }
  }
}

// ---------------- k4: gate = sigma(W_back @ agg) - 0.5 ; out *= gate (unchanged) -------
#define K4_PT 112
__global__ __launch_bounds__(256) void k4_gate(
    const float* __restrict__ agg, const float* __restrict__ Wb,
    float* __restrict__ out)
{
  __shared__ float aggl[RC_][K4_PT];
  const int tid = threadIdx.x;
  const int bt  = blockIdx.y;
  const int b = bt >> 4, t = bt & 15;
  const int p0 = blockIdx.x * K4_PT;
  for (int idx = tid; idx < RC_*K4_PT; idx += 256) {
    int r = idx / K4_PT, p = idx - r*K4_PT;
    aggl[r][p] = agg[((size_t)(b*RC_ + r)*T_ + t)*HW_ + p0 + p];
  }
  __syncthreads();
  const int o = tid;
  float wb[RC_];
  #pragma unroll
  for (int r4 = 0; r4 < RC_; r4 += 4) {
    float4 v = *(const float4*)(Wb + o*RC_ + r4);
    wb[r4] = v.x; wb[r4+1] = v.y; wb[r4+2] = v.z; wb[r4+3] = v.w;
  }
  float* orow = out + ((size_t)(b*C_ + o)*T_ + t)*HW_ + p0;
  for (int p = 0; p < K4_PT; ++p) {
    float g = 0.f;
    #pragma unroll
    for (int r = 0; r < RC_; ++r) g += wb[r] * aggl[r][p];
    float sig = 1.f / (1.f + __expf(-g));
    orow[p] *= (sig - 0.5f);
  }
}

extern "C" void kernel_launch(void* const* d_in, const int* in_sizes, int n_in,
                              void* d_out, int out_size, void* d_ws, size_t ws_size,
                              hipStream_t stream)
{
  const float* x     = (const float*)d_in[0];
  const float* Wd    = (const float*)d_in[1];   // W_down  (16,256)
  const float* W2    = (const float*)d_in[2];   // W_down2 (256,256)
  const float* K1w   = (const float*)d_in[3];
  const float* K2w   = (const float*)d_in[4];
  const float* K3w   = (const float*)d_in[5];
  const float* Wb    = (const float*)d_in[6];   // W_back (256,16)
  const float* wts   = (const float*)d_in[7];   // weights (3)
  const float* w2arr = (const float*)d_in[8];   // weights2 (6)

  const size_t NX2T = (size_t)B_ * T_ * QP_ * C_;     // 6,815,744 elems
  unsigned short* x2t_h = (unsigned short*)d_ws;
  unsigned short* x2c_h = x2t_h + NX2T;
  float* xr  = (float*)(x2c_h + NX2T);                // 401,408 f32
  float* agg = xr + (size_t)B_*RC_*T_*HW_;            // 401,408 f32
  unsigned short* W2h = (unsigned short*)(agg + (size_t)B_*RC_*T_*HW_);
  unsigned short* W2l = W2h + 65536;
  unsigned short* Wdh = W2l + 65536;
  float* out = (float*)d_out;

  k0_prep <<<1808, 256, 0, stream>>>(W2, Wd, x2t_h, x2c_h, W2h, W2l, Wdh);
  k1_mfma <<<dim3(800), 256, 0, stream>>>(x, W2h, W2l, Wdh, x2t_h, x2c_h, xr);
  k2_dwconv<<<dim3(T_, B_*RC_), 256, 0, stream>>>(xr, K1w, K2w, K3w, wts, agg);
  k3_attn_mfma<<<dim3(800), 256, 0, stream>>>(x, x2t_h, x2c_h, w2arr, out);
  k4_gate <<<dim3(HW_/K4_PT, B_*T_), 256, 0, stream>>>(agg, Wb, out);
}

// Round 10
// 393.363 us; speedup vs baseline: 5.8651x; 1.0408x over previous
//
#include <hip/hip_runtime.h>
#include <math.h>

#define B_ 2
#define C_ 256
#define T_ 16
#define H_ 28
#define W_ 28
#define HW_ 784
#define RC_ 16
#define QP_ 832                      // padded key/pixel count (13*64)
#define CT_STRIDE (T_*HW_)

typedef __attribute__((ext_vector_type(8))) short bf16x8;
typedef __attribute__((ext_vector_type(4))) float f32x4;
typedef __attribute__((ext_vector_type(4))) unsigned short u16x4;

__device__ __forceinline__ f32x4 mfma16(bf16x8 a, bf16x8 b, f32x4 c) {
  return __builtin_amdgcn_mfma_f32_16x16x32_bf16(a, b, c, 0, 0, 0);
}
__device__ __forceinline__ unsigned short f2bf(float f) {
  unsigned u = __float_as_uint(f);
  unsigned r = (u + 0x7FFFu + ((u >> 16) & 1u)) >> 16;   // RNE
  return (unsigned short)r;
}
__device__ __forceinline__ float bf2f(unsigned short h) {
  return __uint_as_float((unsigned)h << 16);
}
__device__ __forceinline__ void load8(bf16x8* dst, const unsigned short* p) {
  #pragma unroll
  for (int kk = 0; kk < 8; ++kk) dst[kk] = *(const bf16x8*)(p + kk*32);
}
__device__ __forceinline__ void loadV(bf16x8* dst, const unsigned short* v0, int ch) {
  #pragma unroll
  for (int mt = 0; mt < 4; ++mt) {
    dst[mt*2+0] = *(const bf16x8*)(v0 + (size_t)mt*16*T_*QP_ + (size_t)ch*64);
    dst[mt*2+1] = *(const bf16x8*)(v0 + (size_t)mt*16*T_*QP_ + (size_t)ch*64 + 32);
  }
}
// XCD-aware swizzle for k1 (25 blocks of 32 pixels per frame; 800 blocks)
__device__ __forceinline__ void frame_swizzle(int id, int& b, int& t, int& p0) {
  const int xcd = id & 7;
  const int j   = id >> 3;                 // 0..99
  const int frame = xcd*4 + (j/25);        // 0..31
  const int sub   = j - (j/25)*25;         // 0..24
  b = frame >> 4; t = frame & 15; p0 = sub * 32;
}
// XCD-aware swizzle for k3 (13 blocks of 64 queries per frame; 416 blocks)
__device__ __forceinline__ void frame_swizzle64(int id, int& b, int& t, int& p0) {
  const int xcd = id & 7;
  const int j   = id >> 3;                 // 0..51
  const int frame = xcd*4 + (j/13);        // 0..31
  const int sub   = j - (j/13)*13;         // 0..12
  b = frame >> 4; t = frame & 15; p0 = sub * 64;
}

// ---------------- k0: zero q-pads of x2 buffers + convert W2 -> bf16 hi/lo, Wd -> bf16 -
__global__ __launch_bounds__(256) void k0_prep(
    const float* __restrict__ W2, const float* __restrict__ Wd,
    unsigned short* __restrict__ x2t_h, unsigned short* __restrict__ x2c_h,
    unsigned short* __restrict__ W2h, unsigned short* __restrict__ W2l,
    unsigned short* __restrict__ Wdh)
{
  int i = blockIdx.x * 256 + threadIdx.x;
  if (i < 2*16*48*256) {
    // x2t pads: [b*t][q=784..831][c]
    int bt  = i / (48*256);
    int rem = i - bt*(48*256);
    int q   = 784 + rem / 256;
    int c   = rem & 255;
    x2t_h[((size_t)bt*QP_ + q)*C_ + c] = 0;
    // x2c pads: [b*c*t][q=784..831]
    int bct = i / 48;
    int qq  = 784 + (i - bct*48);
    x2c_h[(size_t)bct*QP_ + qq] = 0;
    return;
  }
  int j = i - 2*16*48*256;
  if (j < 65536) {
    float v = W2[j];
    unsigned short h = f2bf(v);
    W2h[j] = h; W2l[j] = f2bf(v - bf2f(h));
    return;
  }
  int k = j - 65536;
  if (k < 4096) Wdh[k] = f2bf(Wd[k]);
}

// ---------------- k1: MFMA pointwise convs: x2 = W2@x (3-pass hi/lo), xr = Wd@x --------
__global__ __launch_bounds__(256, 2) void k1_mfma(
    const float* __restrict__ x, const unsigned short* __restrict__ W2h,
    const unsigned short* __restrict__ W2l, const unsigned short* __restrict__ Wdh,
    unsigned short* __restrict__ x2t_h, unsigned short* __restrict__ x2c_h,
    float* __restrict__ xr)
{
  __shared__ unsigned short Xth[32][266];   // odd dword-stride (133): <=2-way banks
  __shared__ unsigned short Xtl[32][266];
  const int tid  = threadIdx.x;
  const int lane = tid & 63, wv = tid >> 6;
  const int lm = lane & 15, lg = lane >> 4;
  int b, t, p0;
  frame_swizzle(blockIdx.x, b, t, p0);

  // stage x[c][p0..p0+31] -> Xt[p][c] hi/lo
  {
    const int c = tid;
    const float* xp = x + (((size_t)b*C_ + c)*T_ + t)*HW_ + p0;
    for (int p4 = 0; p4 < 32; p4 += 4) {
      float4 v;
      if (p0 + p4 + 3 < HW_) v = *(const float4*)(xp + p4);
      else { v.x = 0.f; v.y = 0.f; v.z = 0.f; v.w = 0.f; }
      float vv[4] = {v.x, v.y, v.z, v.w};
      #pragma unroll
      for (int jj = 0; jj < 4; ++jj) {
        unsigned short h = f2bf(vv[jj]);
        Xth[p4+jj][c] = h;
        Xtl[p4+jj][c] = f2bf(vv[jj] - bf2f(h));
      }
    }
  }
  __syncthreads();

  // B-fragments (x) in regs: [2 p-tiles][8 kk] hi/lo
  bf16x8 xh[2][8], xl[2][8];
  #pragma unroll
  for (int pt = 0; pt < 2; ++pt)
    #pragma unroll
    for (int kk = 0; kk < 8; ++kk) {
      xh[pt][kk] = *(const bf16x8*)&Xth[pt*16 + lm][kk*32 + lg*8];
      xl[pt][kk] = *(const bf16x8*)&Xtl[pt*16 + lm][kk*32 + lg*8];
    }

  const size_t tb = ((size_t)(b*T_ + t)*QP_);   // x2t frame base (q rows)
  #pragma unroll
  for (int m = 0; m < 4; ++m) {
    const int o0 = wv*64 + m*16;
    bf16x8 ah[8], al[8];
    load8(ah, W2h + (size_t)(o0 + lm)*C_ + lg*8);
    load8(al, W2l + (size_t)(o0 + lm)*C_ + lg*8);
    f32x4 a0 = {0.f,0.f,0.f,0.f}, a1 = {0.f,0.f,0.f,0.f};
    #pragma unroll
    for (int kk = 0; kk < 8; ++kk) { a0 = mfma16(ah[kk], xh[0][kk], a0); a1 = mfma16(ah[kk], xh[1][kk], a1); }
    #pragma unroll
    for (int kk = 0; kk < 8; ++kk) { a0 = mfma16(al[kk], xh[0][kk], a0); a1 = mfma16(al[kk], xh[1][kk], a1); }
    #pragma unroll
    for (int kk = 0; kk < 8; ++kk) { a0 = mfma16(ah[kk], xl[0][kk], a0); a1 = mfma16(ah[kk], xl[1][kk], a1); }
    // epilogue: D[o=(lg,r)][p=lm]
    #pragma unroll
    for (int pt = 0; pt < 2; ++pt) {
      f32x4 a = pt ? a1 : a0;
      const int p = p0 + pt*16 + lm;
      u16x4 hs;
      #pragma unroll
      for (int r = 0; r < 4; ++r) hs[r] = f2bf(a[r]);
      const size_t rowb = (tb + p)*C_ + o0 + lg*4;
      *(u16x4*)&x2t_h[rowb] = hs;
      #pragma unroll
      for (int r = 0; r < 4; ++r) {
        const int c2 = o0 + lg*4 + r;
        x2c_h[(((size_t)b*C_ + c2)*T_ + t)*QP_ + p] = hs[r];
      }
    }
  }
  // xr = Wd @ x (2-pass: Wdh*xh + Wdh*xl), wave 0 only
  if (wv == 0) {
    bf16x8 ad[8];
    load8(ad, Wdh + (size_t)lm*C_ + lg*8);
    f32x4 r0 = {0.f,0.f,0.f,0.f}, r1 = {0.f,0.f,0.f,0.f};
    #pragma unroll
    for (int kk = 0; kk < 8; ++kk) { r0 = mfma16(ad[kk], xh[0][kk], r0); r1 = mfma16(ad[kk], xh[1][kk], r1); }
    #pragma unroll
    for (int kk = 0; kk < 8; ++kk) { r0 = mfma16(ad[kk], xl[0][kk], r0); r1 = mfma16(ad[kk], xl[1][kk], r1); }
    #pragma unroll
    for (int pt = 0; pt < 2; ++pt) {
      const int p = p0 + pt*16 + lm;
      if (p < HW_) {
        f32x4 rr = pt ? r1 : r0;
        #pragma unroll
        for (int r = 0; r < 4; ++r)
          xr[((size_t)(b*RC_ + lg*4 + r)*T_ + t)*HW_ + p] = rr[r];
      }
    }
  }
}

// ---------------- k2: 3x dilated depthwise 3D conv on xr, combined (unchanged) ---------
__global__ __launch_bounds__(256) void k2_dwconv(
    const float* __restrict__ xr, const float* __restrict__ K1w,
    const float* __restrict__ K2w, const float* __restrict__ K3w,
    const float* __restrict__ wts, float* __restrict__ agg)
{
  __shared__ float slab[9][HW_];
  __shared__ float kw[3][81];
  const int tid = threadIdx.x;
  const int t  = blockIdx.x;
  const int br = blockIdx.y;
  const int r = br & 15;
  const size_t chbase = (size_t)br * T_ * HW_;
  for (int idx = tid; idx < 9*HW_; idx += 256) {
    int kd = idx / HW_, pp = idx - kd*HW_;
    int tt = t + kd - 4;
    slab[kd][pp] = (tt >= 0 && tt < T_) ? xr[chbase + (size_t)tt*HW_ + pp] : 0.f;
  }
  for (int idx = tid; idx < 3*81; idx += 256) {
    int kk = idx / 81, rem = idx - kk*81;
    const float* Ksrc = (kk == 0) ? K1w : ((kk == 1) ? K2w : K3w);
    kw[kk][rem] = Ksrc[r*81 + rem];
  }
  __syncthreads();
  const float w0 = wts[0], w1 = wts[1], w2v = wts[2];
  for (int p = tid; p < HW_; p += 256) {
    int h = p / W_, w = p - h*W_;
    float s0 = 0.f, s1 = 0.f, s2 = 0.f;
    for (int kd = 0; kd < 9; ++kd) {
      #pragma unroll
      for (int kh = 0; kh < 3; ++kh) {
        #pragma unroll
        for (int kwi = 0; kwi < 3; ++kwi) {
          const int widx = kd*9 + kh*3 + kwi;
          { int hh = h + (kh-1), ww = w + (kwi-1);
            if (hh >= 0 && hh < H_ && ww >= 0 && ww < W_)
              s0 += kw[0][widx] * slab[kd][hh*W_ + ww]; }
          { int hh = h + (kh-1)*2, ww = w + (kwi-1)*2;
            if (hh >= 0 && hh < H_ && ww >= 0 && ww < W_)
              s1 += kw[1][widx] * slab[kd][hh*W_ + ww]; }
          { int hh = h + (kh-1)*3, ww = w + (kwi-1)*3;
            if (hh >= 0 && hh < H_ && ww >= 0 && ww < W_)
              s2 += kw[2][widx] * slab[kd][hh*W_ + ww]; }
        }
      }
    }
    agg[chbase + (size_t)t*HW_ + p] = w0*s0 + w1*s1 + w2v*s2;
  }
}

// ---------------- k3: MFMA sigmoid-attention, M=64 queries/block, 1-pass bf16 QK^T -----
// Block: 64 queries for one (b,t); 4 waves; wave w owns key-subtile w*16 of each 64-key
// chunk (QK: 4 q-ptiles; ptiles 0-1 from regs, 2-3 from LDS) and channel-quarter w*64
// (PV: O[4 mt][4 nt]). P (64x64) double-buffered in LDS, raw s_barrier per chunk.
#define CHUNK64(KH, KHN, CH, PB, PF)                                           \
{                                                                              \
  bf16x8 vv[8];                                                                \
  loadV(vv, vchunk0, (CH));                    /* V for THIS chunk: in flight */\
  if (PF) load8(KHN, khp0 + (size_t)((CH)+1)*64*C_);  /* next-chunk K_hi */    \
  f32x4 S0 = {0.f,0.f,0.f,0.f}, S1 = {0.f,0.f,0.f,0.f};                        \
  f32x4 S2 = {0.f,0.f,0.f,0.f}, S3 = {0.f,0.f,0.f,0.f};                        \
  _Pragma("unroll")                                                            \
  for (int kk = 0; kk < 8; ++kk) {             /* QK: ptiles 0-1 from regs */  \
    S0 = mfma16(qh[0][kk], KH[kk], S0);                                        \
    S1 = mfma16(qh[1][kk], KH[kk], S1);                                        \
    bf16x8 q2 = *(const bf16x8*)&Qh[32 + lm][kk*32 + lg*8];                    \
    bf16x8 q3 = *(const bf16x8*)&Qh[48 + lm][kk*32 + lg*8];                    \
    S2 = mfma16(q2, KH[kk], S2);                 /* ptiles 2-3 from LDS */     \
    S3 = mfma16(q3, KH[kk], S3);                                               \
  }                                                                            \
  _Pragma("unroll")                                                            \
  for (int r = 0; r < 4; ++r) {                /* sigmoid -> P bf16 */         \
    float pa = wdir * (1.f/(1.f+__expf(-S0[r])) - 0.5f);                       \
    float pb = wdir * (1.f/(1.f+__expf(-S1[r])) - 0.5f);                       \
    float pc = wdir * (1.f/(1.f+__expf(-S2[r])) - 0.5f);                       \
    float pd = wdir * (1.f/(1.f+__expf(-S3[r])) - 0.5f);                       \
    Pls[PB][lg*4+r][wv*16+lm]    = f2bf(pa);                                   \
    Pls[PB][16+lg*4+r][wv*16+lm] = f2bf(pb);                                   \
    Pls[PB][32+lg*4+r][wv*16+lm] = f2bf(pc);                                   \
    Pls[PB][48+lg*4+r][wv*16+lm] = f2bf(pd);                                   \
  }                                                                            \
  __builtin_amdgcn_sched_barrier(0);                                           \
  asm volatile("s_waitcnt lgkmcnt(0)" ::: "memory");                           \
  __builtin_amdgcn_s_barrier();                                                \
  __builtin_amdgcn_sched_barrier(0);                                           \
  {                                                                            \
    _Pragma("unroll")                                                          \
    for (int nt = 0; nt < 4; ++nt) {                                           \
      bf16x8 pb0 = *(const bf16x8*)&Pls[PB][nt*16+lm][lg*8];                   \
      bf16x8 pb1 = *(const bf16x8*)&Pls[PB][nt*16+lm][32+lg*8];                \
      _Pragma("unroll")                                                        \
      for (int mt = 0; mt < 4; ++mt) {                                         \
        O[mt][nt] = mfma16(vv[mt*2+0], pb0, O[mt][nt]);                        \
        O[mt][nt] = mfma16(vv[mt*2+1], pb1, O[mt][nt]);                        \
      }                                                                        \
    }                                                                          \
  }                                                                            \
}

__global__ __launch_bounds__(256, 2) void k3_attn_mfma(
    const float* __restrict__ x, const unsigned short* __restrict__ x2t_h,
    const unsigned short* __restrict__ x2c_h,
    const float* __restrict__ w2arr, float* __restrict__ outF)
{
  __shared__ unsigned short Qh[64][266];   // odd dword-stride: <=2-way banks (34KB)
  __shared__ unsigned short Pls[2][64][74];
  const int tid  = threadIdx.x;
  const int lane = tid & 63, wv = tid >> 6;
  const int lm = lane & 15, lg = lane >> 4;
  int b, t, p0;
  frame_swizzle64(blockIdx.x, b, t, p0);

  // ---- stage Q (bf16 hi only) into LDS: x [c][p] -> Qh[p][c] ----
  {
    const int c = tid;
    const float* xp = x + (((size_t)b*C_ + c)*T_ + t)*HW_ + p0;
    for (int p4 = 0; p4 < 64; p4 += 4) {
      float4 v;
      if (p0 + p4 + 3 < HW_) v = *(const float4*)(xp + p4);
      else { v.x = 0.f; v.y = 0.f; v.z = 0.f; v.w = 0.f; }
      float vvv[4] = {v.x, v.y, v.z, v.w};
      #pragma unroll
      for (int jj = 0; jj < 4; ++jj) Qh[p4+jj][c] = f2bf(vvv[jj]);
    }
  }
  __syncthreads();

  // ---- persistent Qh fragments for ptiles 0-1 (64 VGPRs); 2-3 via LDS per chunk ----
  bf16x8 qh[2][8];
  #pragma unroll
  for (int pt = 0; pt < 2; ++pt)
    #pragma unroll
    for (int kk = 0; kk < 8; ++kk)
      qh[pt][kk] = *(const bf16x8*)&Qh[pt*16 + lm][kk*32 + lg*8];

  f32x4 O[4][4];
  #pragma unroll
  for (int mt = 0; mt < 4; ++mt)
    #pragma unroll
    for (int nt = 0; nt < 4; ++nt)
      O[mt][nt] = (f32x4){0.f, 0.f, 0.f, 0.f};

  const float wd0 = w2arr[0], wd1 = w2arr[1];

  for (int dir = 0; dir < 2; ++dir) {
    const int ts = (dir == 0) ? (t < T_-1 ? t+1 : T_-1) : (t > 0 ? t-1 : 0);
    const float wdir = (dir == 0) ? wd0 : wd1;
    const size_t kf = ((size_t)b*T_ + ts)*QP_;
    const unsigned short* khp0 = x2t_h + (kf + wv*16 + lm)*C_ + lg*8;
    const unsigned short* vchunk0 =
        x2c_h + (((size_t)b*C_ + wv*64 + lm)*T_ + ts)*QP_ + lg*8;

    bf16x8 khA[8], khB[8];
    load8(khA, khp0);                       // chunk-0 K_hi
    for (int cc = 0; cc < 6; ++cc) {
      CHUNK64(khA, khB, (cc*2),   0, 1)
      CHUNK64(khB, khA, (cc*2+1), 1, 1)
    }
    CHUNK64(khA, khB, 12, 0, 0)
    __syncthreads();                         // P-buffer reuse guard across dirs
  }
  // ---- epilogue: O[c][p] -> out ----
  #pragma unroll
  for (int mt = 0; mt < 4; ++mt) {
    const int cbase = wv*64 + mt*16 + lg*4;
    #pragma unroll
    for (int nt = 0; nt < 4; ++nt) {
      const int p = p0 + nt*16 + lm;
      if (p < HW_) {
        #pragma unroll
        for (int r = 0; r < 4; ++r)
          outF[(((size_t)b*C_ + (cbase + r))*T_ + t)*HW_ + p] = O[mt][nt][r];
      }
    }
  }
}

// ---------------- k4: gate = sigma(W_back @ agg) - 0.5 ; out *= gate (unchanged) -------
#define K4_PT 112
__global__ __launch_bounds__(256) void k4_gate(
    const float* __restrict__ agg, const float* __restrict__ Wb,
    float* __restrict__ out)
{
  __shared__ float aggl[RC_][K4_PT];
  const int tid = threadIdx.x;
  const int bt  = blockIdx.y;
  const int b = bt >> 4, t = bt & 15;
  const int p0 = blockIdx.x * K4_PT;
  for (int idx = tid; idx < RC_*K4_PT; idx += 256) {
    int r = idx / K4_PT, p = idx - r*K4_PT;
    aggl[r][p] = agg[((size_t)(b*RC_ + r)*T_ + t)*HW_ + p0 + p];
  }
  __syncthreads();
  const int o = tid;
  float wb[RC_];
  #pragma unroll
  for (int r4 = 0; r4 < RC_; r4 += 4) {
    float4 v = *(const float4*)(Wb + o*RC_ + r4);
    wb[r4] = v.x; wb[r4+1] = v.y; wb[r4+2] = v.z; wb[r4+3] = v.w;
  }
  float* orow = out + ((size_t)(b*C_ + o)*T_ + t)*HW_ + p0;
  for (int p = 0; p < K4_PT; ++p) {
    float g = 0.f;
    #pragma unroll
    for (int r = 0; r < RC_; ++r) g += wb[r] * aggl[r][p];
    float sig = 1.f / (1.f + __expf(-g));
    orow[p] *= (sig - 0.5f);
  }
}

extern "C" void kernel_launch(void* const* d_in, const int* in_sizes, int n_in,
                              void* d_out, int out_size, void* d_ws, size_t ws_size,
                              hipStream_t stream)
{
  const float* x     = (const float*)d_in[0];
  const float* Wd    = (const float*)d_in[1];   // W_down  (16,256)
  const float* W2    = (const float*)d_in[2];   // W_down2 (256,256)
  const float* K1w   = (const float*)d_in[3];
  const float* K2w   = (const float*)d_in[4];
  const float* K3w   = (const float*)d_in[5];
  const float* Wb    = (const float*)d_in[6];   // W_back (256,16)
  const float* wts   = (const float*)d_in[7];   // weights (3)
  const float* w2arr = (const float*)d_in[8];   // weights2 (6)

  const size_t NX2T = (size_t)B_ * T_ * QP_ * C_;     // 6,815,744 elems
  unsigned short* x2t_h = (unsigned short*)d_ws;
  unsigned short* x2c_h = x2t_h + NX2T;
  float* xr  = (float*)(x2c_h + NX2T);                // 401,408 f32
  float* agg = xr + (size_t)B_*RC_*T_*HW_;            // 401,408 f32
  unsigned short* W2h = (unsigned short*)(agg + (size_t)B_*RC_*T_*HW_);
  unsigned short* W2l = W2h + 65536;
  unsigned short* Wdh = W2l + 65536;
  float* out = (float*)d_out;

  k0_prep <<<1808, 256, 0, stream>>>(W2, Wd, x2t_h, x2c_h, W2h, W2l, Wdh);
  k1_mfma <<<dim3(800), 256, 0, stream>>>(x, W2h, W2l, Wdh, x2t_h, x2c_h, xr);
  k2_dwconv<<<dim3(T_, B_*RC_), 256, 0, stream>>>(xr, K1w, K2w, K3w, wts, agg);
  k3_attn_mfma<<<dim3(416), 256, 0, stream>>>(x, x2t_h, x2c_h, w2arr, out);
  k4_gate <<<dim3(HW_/K4_PT, B_*T_), 256, 0, stream>>>(agg, Wb, out);
}